// Round 9
// baseline (3098.420 us; speedup 1.0000x reference)
//
#include <hip/hip_runtime.h>
#include <math.h>

// ---- dims ----
constexpr int B  = 64;
constexpr int S  = 50;
constexpr int W  = 30;
constexpr int E  = 128;
constexpr int H  = 128;
constexpr int NW = B * S;      // 3200 word sequences
constexpr int V  = 50000;      // vocab
constexpr int NSEQ_W = 4;      // word seqs per block (R9: 16->4, TLP over reuse)
constexpr int NSEQ_G = 8;      // rows per block in sl gin GEMM

// ---- intermediates as module-scope device globals ----
__device__ float g_P    [(size_t)2 * V * 512];   // 204.8 MB: emb@Wih^T + biases, per dir
__device__ float g_wl_h [(size_t)NW * W * 256];  // 98.3 MB
__device__ float g_sent [(size_t)NW * 256];      // 3.28 MB
__device__ float g_gin_f[(size_t)NW * 512];      // 6.55 MB
__device__ float g_gin_b[(size_t)NW * 512];      // 6.55 MB
__device__ float g_sl_h [(size_t)B * S * 256];   // 3.28 MB
__device__ float g_doc  [(size_t)B * 256];       // 64 KB

// ---- helpers ----
__device__ __forceinline__ float sigf(float x) { return 1.0f / (1.0f + __expf(-x)); }
__device__ __forceinline__ float tanh_fast(float x) { return 2.0f / (1.0f + __expf(-2.0f * x)) - 1.0f; }
__device__ __forceinline__ float dot4(float4 a, float4 b) {
    return fmaf(a.x, b.x, fmaf(a.y, b.y, fmaf(a.z, b.z, a.w * b.w)));
}

// ============================================================
// K0: vocab input projection: P[dir][v][512] = emb[v]@Wih^T + bih + bhh.
// R9: 16 rows/block (halves Wih L2 re-reads). grid 6250, 256 thr.
// ============================================================
__global__ __launch_bounds__(256) void k_emb_proj(
    const float* __restrict__ emb,
    const float* __restrict__ Wih_f, const float* __restrict__ bih_f, const float* __restrict__ bhh_f,
    const float* __restrict__ Wih_b, const float* __restrict__ bih_b, const float* __restrict__ bhh_b)
{
    const int dir = blockIdx.x & 1;
    const int r0  = (blockIdx.x >> 1) * 16;
    const float* Wih = dir ? Wih_b : Wih_f;
    const float* bih = dir ? bih_b : bih_f;
    const float* bhh = dir ? bhh_b : bhh_f;

    __shared__ float xs[16][E];   // 8 KB
    const int tid = threadIdx.x;
    for (int i = tid * 4; i < 16 * E; i += 1024)
        *(float4*)&(&xs[0][0])[i] = *(const float4*)&emb[(size_t)r0 * E + i];
    __syncthreads();

    const int g0 = tid, g1 = tid + 256;
    const float* w0 = &Wih[(size_t)g0 * E];
    const float* w1 = &Wih[(size_t)g1 * E];
    float acc0[16], acc1[16];
    #pragma unroll
    for (int r = 0; r < 16; ++r) { acc0[r] = 0.f; acc1[r] = 0.f; }
    for (int k = 0; k < E; k += 4) {
        float4 wa = *(const float4*)(w0 + k);
        float4 wb = *(const float4*)(w1 + k);
        #pragma unroll
        for (int r = 0; r < 16; ++r) {
            float4 xv = *(const float4*)&xs[r][k];
            acc0[r] += dot4(wa, xv);
            acc1[r] += dot4(wb, xv);
        }
    }
    const float bv0 = bih[g0] + bhh[g0];
    const float bv1 = bih[g1] + bhh[g1];
    float* P = g_P + (size_t)dir * V * 512;
    #pragma unroll
    for (int r = 0; r < 16; ++r) {
        P[(size_t)(r0 + r) * 512 + g0] = acc0[r] + bv0;
        P[(size_t)(r0 + r) * 512 + g1] = acc1[r] + bv1;
    }
}

// ============================================================
// K1: word BiLSTM recurrence. Thread j (128 thr) owns ALL 4 gates of
// cell j for NSEQ_W=4 seqs: cell update in-thread, c in regs, ONE
// barrier/step. grid = (3200/4)*2 = 1600 blocks -> ~12.5 waves/CU.
// LDS 4.5 KB.
// ============================================================
__global__ __launch_bounds__(128) void k_word_lstm(
    const int* __restrict__ ids,
    const float* __restrict__ Whh_f, const float* __restrict__ Whh_b)
{
    const int dir = blockIdx.x & 1;
    const int s0  = (blockIdx.x >> 1) * NSEQ_W;
    const float* Whh = dir ? Whh_b : Whh_f;
    const float* Pp  = g_P + (size_t)dir * V * 512;

    __shared__ float hs[2][NSEQ_W][H];   // 4 KB double-buffered
    __shared__ int   ids_sh[NSEQ_W * W]; // 480 B

    const int j = threadIdx.x;           // cell index 0..127
    if (j < NSEQ_W * W) ids_sh[j] = ids[s0 * W + j];
    for (int i = j; i < 2 * NSEQ_W * H; i += 128) (&hs[0][0][0])[i] = 0.f;

    const float* wr0 = Whh + (size_t)(j      ) * H;
    const float* wr1 = Whh + (size_t)(j + 128) * H;
    const float* wr2 = Whh + (size_t)(j + 256) * H;
    const float* wr3 = Whh + (size_t)(j + 384) * H;

    float cst[NSEQ_W];
    #pragma unroll
    for (int s = 0; s < NSEQ_W; ++s) cst[s] = 0.f;

    __syncthreads();

    int cur = 0;
    for (int st = 0; st < W; ++st) {
        const int t = dir ? (W - 1 - st) : st;

        // P gathers issued before the k-loop; values consumed after it,
        // so the ~4096-cycle FMA body hides the HBM/L2 latency.
        float pg0[NSEQ_W], pg1[NSEQ_W], pg2[NSEQ_W], pg3[NSEQ_W];
        #pragma unroll
        for (int s = 0; s < NSEQ_W; ++s) {
            const float* Pr = Pp + (size_t)ids_sh[s * W + t] * 512;
            pg0[s] = Pr[j];
            pg1[s] = Pr[j + 128];
            pg2[s] = Pr[j + 256];
            pg3[s] = Pr[j + 384];
        }

        float a0[NSEQ_W], a1[NSEQ_W], a2[NSEQ_W], a3[NSEQ_W];
        #pragma unroll
        for (int s = 0; s < NSEQ_W; ++s) { a0[s] = 0.f; a1[s] = 0.f; a2[s] = 0.f; a3[s] = 0.f; }

        for (int k = 0; k < H; k += 4) {
            float4 w0 = *(const float4*)(wr0 + k);
            float4 w1 = *(const float4*)(wr1 + k);
            float4 w2 = *(const float4*)(wr2 + k);
            float4 w3 = *(const float4*)(wr3 + k);
            #pragma unroll
            for (int s = 0; s < NSEQ_W; ++s) {
                float4 hv = *(const float4*)&hs[cur][s][k];  // wave-uniform: LDS broadcast
                a0[s] += dot4(w0, hv);
                a1[s] += dot4(w1, hv);
                a2[s] += dot4(w2, hv);
                a3[s] += dot4(w3, hv);
            }
        }

        #pragma unroll
        for (int s = 0; s < NSEQ_W; ++s) {
            float c = sigf(a1[s] + pg1[s]) * cst[s]
                    + sigf(a0[s] + pg0[s]) * tanh_fast(a2[s] + pg2[s]);
            float h = sigf(a3[s] + pg3[s]) * tanh_fast(c);
            cst[s] = c;
            hs[cur ^ 1][s][j] = h;
            g_wl_h[((size_t)(s0 + s) * W + t) * 256 + dir * H + j] = h;
        }
        __syncthreads();
        cur ^= 1;
    }
}

// ============================================================
// K2: word attention pool, SINGLE-PASS (30.7 KB LDS). grid NW, 128 thr.
// ============================================================
template <int T>
__global__ __launch_bounds__(128) void k_attn_pool_word(
    const int* __restrict__ ids,
    const float* __restrict__ W1, const float* __restrict__ b1,
    const float* __restrict__ W2, const float* __restrict__ b2)
{
    constexpr int TH = T / 2;
    const int n = blockIdx.x;
    __shared__ float hsh[T][256];
    __shared__ float wsh[T];
    const int tid = threadIdx.x;
    const int lane = tid & 63;
    const int wv   = tid >> 6;

    const float* src = g_wl_h + (size_t)n * T * 256;
    for (int i = tid * 4; i < T * 256; i += 512)
        *(float4*)&(&hsh[0][0])[i] = *(const float4*)&src[i];
    __syncthreads();

    const int j0 = lane, j1 = lane + 64;
    const int tbase = wv * TH;
    float acc0[TH], acc1[TH];
    #pragma unroll
    for (int u = 0; u < TH; ++u) { acc0[u] = 0.f; acc1[u] = 0.f; }
    const float* w1a = &W1[j0 * 256];
    const float* w1b = &W1[j1 * 256];
    for (int k = 0; k < 256; k += 4) {
        float4 wa = *(const float4*)(w1a + k);
        float4 wb = *(const float4*)(w1b + k);
        #pragma unroll
        for (int u = 0; u < TH; ++u) {
            float4 hv = *(const float4*)&hsh[tbase + u][k];
            acc0[u] += dot4(wa, hv);
            acc1[u] += dot4(wb, hv);
        }
    }
    const float b1a = b1[j0], b1b = b1[j1];
    const float w2a = W2[j0], w2b = W2[j1];
    #pragma unroll
    for (int u = 0; u < TH; ++u) {
        float v = w2a * tanh_fast(acc0[u] + b1a) + w2b * tanh_fast(acc1[u] + b1b);
        #pragma unroll
        for (int off = 32; off > 0; off >>= 1) v += __shfl_down(v, off, 64);
        if (lane == 0) wsh[tbase + u] = v;
    }
    __syncthreads();

    if (tid < T) {
        bool valid = (ids[n * T + tid] != 0);
        wsh[tid] = valid ? (wsh[tid] + b2[0]) : -INFINITY;
    }
    __syncthreads();
    if (tid == 0) {
        float m = -INFINITY;
        for (int t = 0; t < T; ++t) m = fmaxf(m, wsh[t]);
        float sum = 0.f;
        for (int t = 0; t < T; ++t) sum += (wsh[t] == -INFINITY) ? 0.f : __expf(wsh[t] - m);
        const float inv = (sum > 0.f) ? 1.f / sum : 0.f;
        for (int t = 0; t < T; ++t) wsh[t] = (wsh[t] == -INFINITY) ? 0.f : __expf(wsh[t] - m) * inv;
    }
    __syncthreads();

    float o0 = 0.f, o1 = 0.f;
    #pragma unroll
    for (int t = 0; t < T; ++t) {
        float w = wsh[t];
        o0 += w * hsh[t][tid];
        o1 += w * hsh[t][tid + 128];
    }
    g_sent[(size_t)n * 256 + tid] = o0;
    g_sent[(size_t)n * 256 + tid + 128] = o1;
}

// ============================================================
// K3: sentence LSTM input projection. grid 800, 256 thr.
// ============================================================
__global__ __launch_bounds__(256) void k_sl_gin(
    const float* __restrict__ Wih_f, const float* __restrict__ bih_f, const float* __restrict__ bhh_f,
    const float* __restrict__ Wih_b, const float* __restrict__ bih_b, const float* __restrict__ bhh_b)
{
    const int dir = blockIdx.x & 1;
    const float* Wih = dir ? Wih_b : Wih_f;
    const float* bih = dir ? bih_b : bih_f;
    const float* bhh = dir ? bhh_b : bhh_f;
    float* gin = dir ? g_gin_b : g_gin_f;
    const int r0 = (blockIdx.x >> 1) * NSEQ_G;

    __shared__ float xs[NSEQ_G][256];
    const int tid = threadIdx.x;
    for (int i = tid * 4; i < NSEQ_G * 256; i += 1024)
        *(float4*)&(&xs[0][0])[i] = *(const float4*)&g_sent[(size_t)r0 * 256 + i];
    __syncthreads();

    const int g0 = tid, g1 = tid + 256;
    float acc0[NSEQ_G], acc1[NSEQ_G];
    #pragma unroll
    for (int s = 0; s < NSEQ_G; ++s) { acc0[s] = 0.f; acc1[s] = 0.f; }
    const float* w0 = &Wih[g0 * 256]; const float* w1 = &Wih[g1 * 256];
    for (int k = 0; k < 256; k += 4) {
        float4 wa = *(const float4*)(w0 + k);
        float4 wb = *(const float4*)(w1 + k);
        #pragma unroll
        for (int s = 0; s < NSEQ_G; ++s) {
            float4 xv = *(const float4*)&xs[s][k];
            acc0[s] += dot4(wa, xv);
            acc1[s] += dot4(wb, xv);
        }
    }
    const float bv0 = bih[g0] + bhh[g0];
    const float bv1 = bih[g1] + bhh[g1];
    #pragma unroll
    for (int s = 0; s < NSEQ_G; ++s) {
        gin[(size_t)(r0 + s) * 512 + g0] = acc0[s] + bv0;
        gin[(size_t)(r0 + s) * 512 + g1] = acc1[s] + bv1;
    }
}

// ============================================================
// K4: sentence BiLSTM, owns-cell, 1 seq/block. grid 128, 128 thr.
// ============================================================
__global__ __launch_bounds__(128) void k_sent_lstm(
    const float* __restrict__ Whh_f, const float* __restrict__ Whh_b)
{
    const int dir = blockIdx.x & 1;
    const int b   = blockIdx.x >> 1;
    const float* Whh = dir ? Whh_b : Whh_f;
    const float* gin = dir ? g_gin_b : g_gin_f;

    __shared__ float hs[2][H];
    const int j = threadIdx.x;
    const float* wr0 = Whh + (size_t)(j      ) * H;
    const float* wr1 = Whh + (size_t)(j + 128) * H;
    const float* wr2 = Whh + (size_t)(j + 256) * H;
    const float* wr3 = Whh + (size_t)(j + 384) * H;

    hs[0][j] = 0.f;
    float cst = 0.f;
    __syncthreads();

    int cur = 0;
    for (int st = 0; st < S; ++st) {
        const int t = dir ? (S - 1 - st) : st;
        const float* gp = gin + (size_t)(b * S + t) * 512;
        float p0 = gp[j], p1 = gp[j + 128], p2 = gp[j + 256], p3 = gp[j + 384];

        float a0 = 0.f, a1 = 0.f, a2 = 0.f, a3 = 0.f;
        for (int k = 0; k < H; k += 4) {
            float4 hv = *(const float4*)&hs[cur][k];
            a0 += dot4(*(const float4*)(wr0 + k), hv);
            a1 += dot4(*(const float4*)(wr1 + k), hv);
            a2 += dot4(*(const float4*)(wr2 + k), hv);
            a3 += dot4(*(const float4*)(wr3 + k), hv);
        }
        float c = sigf(a1 + p1) * cst + sigf(a0 + p0) * tanh_fast(a2 + p2);
        float h = sigf(a3 + p3) * tanh_fast(c);
        cst = c;
        hs[cur ^ 1][j] = h;
        g_sl_h[(size_t)(b * S + t) * 256 + dir * H + j] = h;
        __syncthreads();
        cur ^= 1;
    }
}

// ============================================================
// K5: document attention pool, SINGLE-PASS (51.2 KB LDS). grid B, 128 thr.
// ============================================================
template <int T>
__global__ __launch_bounds__(128) void k_attn_pool_doc(
    const int* __restrict__ ids,
    const float* __restrict__ W1, const float* __restrict__ b1,
    const float* __restrict__ W2, const float* __restrict__ b2)
{
    constexpr int TH = T / 2;
    const int n = blockIdx.x;
    __shared__ float hsh[T][256];
    __shared__ float wsh[T];
    const int tid = threadIdx.x;
    const int lane = tid & 63;
    const int wv   = tid >> 6;

    const float* src = g_sl_h + (size_t)n * T * 256;
    for (int i = tid * 4; i < T * 256; i += 512)
        *(float4*)&(&hsh[0][0])[i] = *(const float4*)&src[i];
    __syncthreads();

    const int j0 = lane, j1 = lane + 64;
    const int tbase = wv * TH;
    float acc0[TH], acc1[TH];
    #pragma unroll
    for (int u = 0; u < TH; ++u) { acc0[u] = 0.f; acc1[u] = 0.f; }
    const float* w1a = &W1[j0 * 256];
    const float* w1b = &W1[j1 * 256];
    for (int k = 0; k < 256; k += 4) {
        float4 wa = *(const float4*)(w1a + k);
        float4 wb = *(const float4*)(w1b + k);
        #pragma unroll
        for (int u = 0; u < TH; ++u) {
            float4 hv = *(const float4*)&hsh[tbase + u][k];
            acc0[u] += dot4(wa, hv);
            acc1[u] += dot4(wb, hv);
        }
    }
    const float b1a = b1[j0], b1b = b1[j1];
    const float w2a = W2[j0], w2b = W2[j1];
    #pragma unroll
    for (int u = 0; u < TH; ++u) {
        float v = w2a * tanh_fast(acc0[u] + b1a) + w2b * tanh_fast(acc1[u] + b1b);
        #pragma unroll
        for (int off = 32; off > 0; off >>= 1) v += __shfl_down(v, off, 64);
        if (lane == 0) wsh[tbase + u] = v;
    }
    __syncthreads();

    if (tid < T) {
        bool valid = false;
        const int* ip = &ids[((size_t)n * T + tid) * W];
        for (int w = 0; w < W; ++w) valid |= (ip[w] != 0);
        wsh[tid] = valid ? (wsh[tid] + b2[0]) : -INFINITY;
    }
    __syncthreads();
    if (tid == 0) {
        float m = -INFINITY;
        for (int t = 0; t < T; ++t) m = fmaxf(m, wsh[t]);
        float sum = 0.f;
        for (int t = 0; t < T; ++t) sum += (wsh[t] == -INFINITY) ? 0.f : __expf(wsh[t] - m);
        const float inv = (sum > 0.f) ? 1.f / sum : 0.f;
        for (int t = 0; t < T; ++t) wsh[t] = (wsh[t] == -INFINITY) ? 0.f : __expf(wsh[t] - m) * inv;
    }
    __syncthreads();

    float o0 = 0.f, o1 = 0.f;
    #pragma unroll
    for (int t = 0; t < T; ++t) {
        float w = wsh[t];
        o0 += w * hsh[t][tid];
        o1 += w * hsh[t][tid + 128];
    }
    g_doc[(size_t)n * 256 + tid] = o0;
    g_doc[(size_t)n * 256 + tid + 128] = o1;
}

// ============================================================
// K6: classifier (fp32 out). grid B, 128 thr.
// ============================================================
__global__ __launch_bounds__(128) void k_classifier(
    const float* __restrict__ W1, const float* __restrict__ b1,
    const float* __restrict__ W2, const float* __restrict__ b2,
    float* __restrict__ out)
{
    const int b = blockIdx.x;
    __shared__ float dsh[256];
    __shared__ float hsh[128];
    const int tid = threadIdx.x;
    if (tid < 64) *(float4*)&dsh[tid * 4] = *(const float4*)&g_doc[(size_t)b * 256 + tid * 4];
    __syncthreads();
    float acc = 0.f;
    const float* w1p = &W1[tid * 256];
    for (int k = 0; k < 256; k += 4) {
        float4 w4 = *(const float4*)(w1p + k);
        float4 d4 = *(const float4*)&dsh[k];
        acc += dot4(w4, d4);
    }
    hsh[tid] = fmaxf(acc + b1[tid], 0.f);
    __syncthreads();
    if (tid < 3) {
        float a = b2[tid];
        const float* w2p = &W2[tid * 128];
        for (int j = 0; j < 128; ++j) a += w2p[j] * hsh[j];
        out[b * 3 + tid] = a;
    }
}

// ============================================================
extern "C" void kernel_launch(void* const* d_in, const int* in_sizes, int n_in,
                              void* d_out, int out_size, void* d_ws, size_t ws_size,
                              hipStream_t stream) {
    const int*   ids      = (const int*)d_in[0];
    const float* emb      = (const float*)d_in[1];
    const float* wl_Wih_f = (const float*)d_in[2];
    const float* wl_Whh_f = (const float*)d_in[3];
    const float* wl_bih_f = (const float*)d_in[4];
    const float* wl_bhh_f = (const float*)d_in[5];
    const float* wl_Wih_b = (const float*)d_in[6];
    const float* wl_Whh_b = (const float*)d_in[7];
    const float* wl_bih_b = (const float*)d_in[8];
    const float* wl_bhh_b = (const float*)d_in[9];
    const float* sl_Wih_f = (const float*)d_in[10];
    const float* sl_Whh_f = (const float*)d_in[11];
    const float* sl_bih_f = (const float*)d_in[12];
    const float* sl_bhh_f = (const float*)d_in[13];
    const float* sl_Wih_b = (const float*)d_in[14];
    const float* sl_Whh_b = (const float*)d_in[15];
    const float* sl_bih_b = (const float*)d_in[16];
    const float* sl_bhh_b = (const float*)d_in[17];
    const float* wa_W1 = (const float*)d_in[18];
    const float* wa_b1 = (const float*)d_in[19];
    const float* wa_W2 = (const float*)d_in[20];
    const float* wa_b2 = (const float*)d_in[21];
    const float* sa_W1 = (const float*)d_in[22];
    const float* sa_b1 = (const float*)d_in[23];
    const float* sa_W2 = (const float*)d_in[24];
    const float* sa_b2 = (const float*)d_in[25];
    const float* cl_W1 = (const float*)d_in[26];
    const float* cl_b1 = (const float*)d_in[27];
    const float* cl_W2 = (const float*)d_in[28];
    const float* cl_b2 = (const float*)d_in[29];

    k_emb_proj<<<(V / 16) * 2, 256, 0, stream>>>(
        emb, wl_Wih_f, wl_bih_f, wl_bhh_f, wl_Wih_b, wl_bih_b, wl_bhh_b);

    k_word_lstm<<<NW / NSEQ_W * 2, 128, 0, stream>>>(ids, wl_Whh_f, wl_Whh_b);

    k_attn_pool_word<W><<<NW, 128, 0, stream>>>(ids, wa_W1, wa_b1, wa_W2, wa_b2);

    k_sl_gin<<<NW / NSEQ_G * 2, 256, 0, stream>>>(
        sl_Wih_f, sl_bih_f, sl_bhh_f, sl_Wih_b, sl_bih_b, sl_bhh_b);

    k_sent_lstm<<<B * 2, 128, 0, stream>>>(sl_Whh_f, sl_Whh_b);

    k_attn_pool_doc<S><<<B, 128, 0, stream>>>(ids, sa_W1, sa_b1, sa_W2, sa_b2);

    k_classifier<<<B, 128, 0, stream>>>(cl_W1, cl_b1, cl_W2, cl_b2, (float*)d_out);
}

// Round 10
// 2211.909 us; speedup vs baseline: 1.4008x; 1.4008x over previous
//
#include <hip/hip_runtime.h>
#include <math.h>

// ---- dims ----
constexpr int B  = 64;
constexpr int S  = 50;
constexpr int W  = 30;
constexpr int E  = 128;
constexpr int H  = 128;
constexpr int NW = B * S;      // 3200 word sequences
constexpr int V  = 50000;      // vocab
constexpr int NSEQ_W = 8;      // word seqs per block (512-thr owns-row version)
constexpr int NSEQ_G = 8;      // rows per block in sl gin GEMM

// ---- intermediates as module-scope device globals ----
__device__ float g_P    [(size_t)2 * V * 512];   // 204.8 MB: emb@Wih^T + biases, per dir
__device__ float g_wl_h [(size_t)NW * W * 256];  // 98.3 MB
__device__ float g_sent [(size_t)NW * 256];      // 3.28 MB
__device__ float g_gin_f[(size_t)NW * 512];      // 6.55 MB
__device__ float g_gin_b[(size_t)NW * 512];      // 6.55 MB
__device__ float g_sl_h [(size_t)B * S * 256];   // 3.28 MB
__device__ float g_doc  [(size_t)B * 256];       // 64 KB

// ---- helpers ----
__device__ __forceinline__ float sigf(float x) { return 1.0f / (1.0f + __expf(-x)); }
__device__ __forceinline__ float tanh_fast(float x) { return 2.0f / (1.0f + __expf(-2.0f * x)) - 1.0f; }
__device__ __forceinline__ float dot4(float4 a, float4 b) {
    return fmaf(a.x, b.x, fmaf(a.y, b.y, fmaf(a.z, b.z, a.w * b.w)));
}

// ============================================================
// K0: vocab input projection: P[dir][v][512] = emb[v]@Wih^T + bih + bhh.
// 16 rows/block. grid 6250, 256 thr.
// ============================================================
__global__ __launch_bounds__(256) void k_emb_proj(
    const float* __restrict__ emb,
    const float* __restrict__ Wih_f, const float* __restrict__ bih_f, const float* __restrict__ bhh_f,
    const float* __restrict__ Wih_b, const float* __restrict__ bih_b, const float* __restrict__ bhh_b)
{
    const int dir = blockIdx.x & 1;
    const int r0  = (blockIdx.x >> 1) * 16;
    const float* Wih = dir ? Wih_b : Wih_f;
    const float* bih = dir ? bih_b : bih_f;
    const float* bhh = dir ? bhh_b : bhh_f;

    __shared__ float xs[16][E];   // 8 KB
    const int tid = threadIdx.x;
    for (int i = tid * 4; i < 16 * E; i += 1024)
        *(float4*)&(&xs[0][0])[i] = *(const float4*)&emb[(size_t)r0 * E + i];
    __syncthreads();

    const int g0 = tid, g1 = tid + 256;
    const float* w0 = &Wih[(size_t)g0 * E];
    const float* w1 = &Wih[(size_t)g1 * E];
    float acc0[16], acc1[16];
    #pragma unroll
    for (int r = 0; r < 16; ++r) { acc0[r] = 0.f; acc1[r] = 0.f; }
    for (int k = 0; k < E; k += 4) {
        float4 wa = *(const float4*)(w0 + k);
        float4 wb = *(const float4*)(w1 + k);
        #pragma unroll
        for (int r = 0; r < 16; ++r) {
            float4 xv = *(const float4*)&xs[r][k];
            acc0[r] += dot4(wa, xv);
            acc1[r] += dot4(wb, xv);
        }
    }
    const float bv0 = bih[g0] + bhh[g0];
    const float bv1 = bih[g1] + bhh[g1];
    float* P = g_P + (size_t)dir * V * 512;
    #pragma unroll
    for (int r = 0; r < 16; ++r) {
        P[(size_t)(r0 + r) * 512 + g0] = acc0[r] + bv0;
        P[(size_t)(r0 + r) * 512 + g1] = acc1[r] + bv1;
    }
}

// ============================================================
// K1: word BiLSTM recurrence, WEIGHTS-IN-REGISTERS.
// 512 thr: thread (g=tid>>7, j=tid&127) owns Whh row g*128+j in 32
// float4 regs, loaded ONCE. Per step: coalesced P-row gather (2 KB/row),
// LDS-broadcast h dot, gate exchange via gs LDS, distributed update.
// Zero global weight traffic in the time loop. grid 800, LDS 25 KB.
// ============================================================
__global__ __launch_bounds__(512) void k_word_lstm(
    const int* __restrict__ ids,
    const float* __restrict__ Whh_f, const float* __restrict__ Whh_b)
{
    const int dir = blockIdx.x & 1;
    const int s0  = (blockIdx.x >> 1) * NSEQ_W;
    const float* Whh = dir ? Whh_b : Whh_f;
    const float* Pp  = g_P + (size_t)dir * V * 512;

    __shared__ float hs[2][NSEQ_W][H];     // 8 KB double-buffered
    __shared__ float gs[4][NSEQ_W][H];     // 16 KB gate exchange
    __shared__ int   ids_sh[NSEQ_W * W];   // 960 B

    const int tid = threadIdx.x;
    const int g   = tid >> 7;     // gate 0..3
    const int j   = tid & 127;    // cell 0..127

    // persistent weight row (128 floats = 32 float4 VGPRs)
    const float* wr = Whh + (size_t)(g * H + j) * H;
    float4 wreg[32];
    #pragma unroll
    for (int c = 0; c < 32; ++c) wreg[c] = *(const float4*)(wr + c * 4);

    for (int i = tid; i < NSEQ_W * W; i += 512) ids_sh[i] = ids[s0 * W + i];
    for (int i = tid; i < 2 * NSEQ_W * H; i += 512) (&hs[0][0][0])[i] = 0.f;

    float cst[2] = {0.f, 0.f};    // c-state for seqs (tid>>7) and (tid>>7)+4
    __syncthreads();

    int cur = 0;
    for (int st = 0; st < W; ++st) {
        const int t = dir ? (W - 1 - st) : st;

        // coalesced P gathers (one 2KB row per seq), consumed after k-loop
        float pg[NSEQ_W];
        #pragma unroll
        for (int s = 0; s < NSEQ_W; ++s)
            pg[s] = Pp[(size_t)ids_sh[s * W + t] * 512 + g * H + j];

        float acc[NSEQ_W];
        #pragma unroll
        for (int s = 0; s < NSEQ_W; ++s) acc[s] = 0.f;

        #pragma unroll
        for (int c = 0; c < 32; ++c) {
            #pragma unroll
            for (int s = 0; s < NSEQ_W; ++s) {
                float4 hv = *(const float4*)&hs[cur][s][c * 4];  // wave-uniform: broadcast
                acc[s] += dot4(wreg[c], hv);
            }
        }

        #pragma unroll
        for (int s = 0; s < NSEQ_W; ++s) gs[g][s][j] = acc[s] + pg[s];
        __syncthreads();

        // distributed cell update: thread handles seqs (tid>>7) and (tid>>7)+4
        #pragma unroll
        for (int r = 0; r < 2; ++r) {
            const int s = (tid >> 7) + r * 4;
            float gi = gs[0][s][j], gf = gs[1][s][j];
            float gg = gs[2][s][j], go = gs[3][s][j];
            float c = sigf(gf) * cst[r] + sigf(gi) * tanh_fast(gg);
            float h = sigf(go) * tanh_fast(c);
            cst[r] = c;
            hs[cur ^ 1][s][j] = h;
            g_wl_h[((size_t)(s0 + s) * W + t) * 256 + dir * H + j] = h;
        }
        __syncthreads();
        cur ^= 1;
    }
}

// ============================================================
// K2: word attention pool, SINGLE-PASS (30.7 KB LDS). grid NW, 128 thr.
// ============================================================
template <int T>
__global__ __launch_bounds__(128) void k_attn_pool_word(
    const int* __restrict__ ids,
    const float* __restrict__ W1, const float* __restrict__ b1,
    const float* __restrict__ W2, const float* __restrict__ b2)
{
    constexpr int TH = T / 2;
    const int n = blockIdx.x;
    __shared__ float hsh[T][256];
    __shared__ float wsh[T];
    const int tid = threadIdx.x;
    const int lane = tid & 63;
    const int wv   = tid >> 6;

    const float* src = g_wl_h + (size_t)n * T * 256;
    for (int i = tid * 4; i < T * 256; i += 512)
        *(float4*)&(&hsh[0][0])[i] = *(const float4*)&src[i];
    __syncthreads();

    const int j0 = lane, j1 = lane + 64;
    const int tbase = wv * TH;
    float acc0[TH], acc1[TH];
    #pragma unroll
    for (int u = 0; u < TH; ++u) { acc0[u] = 0.f; acc1[u] = 0.f; }
    const float* w1a = &W1[j0 * 256];
    const float* w1b = &W1[j1 * 256];
    for (int k = 0; k < 256; k += 4) {
        float4 wa = *(const float4*)(w1a + k);
        float4 wb = *(const float4*)(w1b + k);
        #pragma unroll
        for (int u = 0; u < TH; ++u) {
            float4 hv = *(const float4*)&hsh[tbase + u][k];
            acc0[u] += dot4(wa, hv);
            acc1[u] += dot4(wb, hv);
        }
    }
    const float b1a = b1[j0], b1b = b1[j1];
    const float w2a = W2[j0], w2b = W2[j1];
    #pragma unroll
    for (int u = 0; u < TH; ++u) {
        float v = w2a * tanh_fast(acc0[u] + b1a) + w2b * tanh_fast(acc1[u] + b1b);
        #pragma unroll
        for (int off = 32; off > 0; off >>= 1) v += __shfl_down(v, off, 64);
        if (lane == 0) wsh[tbase + u] = v;
    }
    __syncthreads();

    if (tid < T) {
        bool valid = (ids[n * T + tid] != 0);
        wsh[tid] = valid ? (wsh[tid] + b2[0]) : -INFINITY;
    }
    __syncthreads();
    if (tid == 0) {
        float m = -INFINITY;
        for (int t = 0; t < T; ++t) m = fmaxf(m, wsh[t]);
        float sum = 0.f;
        for (int t = 0; t < T; ++t) sum += (wsh[t] == -INFINITY) ? 0.f : __expf(wsh[t] - m);
        const float inv = (sum > 0.f) ? 1.f / sum : 0.f;
        for (int t = 0; t < T; ++t) wsh[t] = (wsh[t] == -INFINITY) ? 0.f : __expf(wsh[t] - m) * inv;
    }
    __syncthreads();

    float o0 = 0.f, o1 = 0.f;
    #pragma unroll
    for (int t = 0; t < T; ++t) {
        float w = wsh[t];
        o0 += w * hsh[t][tid];
        o1 += w * hsh[t][tid + 128];
    }
    g_sent[(size_t)n * 256 + tid] = o0;
    g_sent[(size_t)n * 256 + tid + 128] = o1;
}

// ============================================================
// K3: sentence LSTM input projection. grid 800, 256 thr.
// ============================================================
__global__ __launch_bounds__(256) void k_sl_gin(
    const float* __restrict__ Wih_f, const float* __restrict__ bih_f, const float* __restrict__ bhh_f,
    const float* __restrict__ Wih_b, const float* __restrict__ bih_b, const float* __restrict__ bhh_b)
{
    const int dir = blockIdx.x & 1;
    const float* Wih = dir ? Wih_b : Wih_f;
    const float* bih = dir ? bih_b : bih_f;
    const float* bhh = dir ? bhh_b : bhh_f;
    float* gin = dir ? g_gin_b : g_gin_f;
    const int r0 = (blockIdx.x >> 1) * NSEQ_G;

    __shared__ float xs[NSEQ_G][256];
    const int tid = threadIdx.x;
    for (int i = tid * 4; i < NSEQ_G * 256; i += 1024)
        *(float4*)&(&xs[0][0])[i] = *(const float4*)&g_sent[(size_t)r0 * 256 + i];
    __syncthreads();

    const int g0 = tid, g1 = tid + 256;
    float acc0[NSEQ_G], acc1[NSEQ_G];
    #pragma unroll
    for (int s = 0; s < NSEQ_G; ++s) { acc0[s] = 0.f; acc1[s] = 0.f; }
    const float* w0 = &Wih[g0 * 256]; const float* w1 = &Wih[g1 * 256];
    for (int k = 0; k < 256; k += 4) {
        float4 wa = *(const float4*)(w0 + k);
        float4 wb = *(const float4*)(w1 + k);
        #pragma unroll
        for (int s = 0; s < NSEQ_G; ++s) {
            float4 xv = *(const float4*)&xs[s][k];
            acc0[s] += dot4(wa, xv);
            acc1[s] += dot4(wb, xv);
        }
    }
    const float bv0 = bih[g0] + bhh[g0];
    const float bv1 = bih[g1] + bhh[g1];
    #pragma unroll
    for (int s = 0; s < NSEQ_G; ++s) {
        gin[(size_t)(r0 + s) * 512 + g0] = acc0[s] + bv0;
        gin[(size_t)(r0 + s) * 512 + g1] = acc1[s] + bv1;
    }
}

// ============================================================
// K4: sentence BiLSTM, owns-cell, 1 seq/block. grid 128, 128 thr.
// ============================================================
__global__ __launch_bounds__(128) void k_sent_lstm(
    const float* __restrict__ Whh_f, const float* __restrict__ Whh_b)
{
    const int dir = blockIdx.x & 1;
    const int b   = blockIdx.x >> 1;
    const float* Whh = dir ? Whh_b : Whh_f;
    const float* gin = dir ? g_gin_b : g_gin_f;

    __shared__ float hs[2][H];
    const int j = threadIdx.x;
    const float* wr0 = Whh + (size_t)(j      ) * H;
    const float* wr1 = Whh + (size_t)(j + 128) * H;
    const float* wr2 = Whh + (size_t)(j + 256) * H;
    const float* wr3 = Whh + (size_t)(j + 384) * H;

    hs[0][j] = 0.f;
    float cst = 0.f;
    __syncthreads();

    int cur = 0;
    for (int st = 0; st < S; ++st) {
        const int t = dir ? (S - 1 - st) : st;
        const float* gp = gin + (size_t)(b * S + t) * 512;
        float p0 = gp[j], p1 = gp[j + 128], p2 = gp[j + 256], p3 = gp[j + 384];

        float a0 = 0.f, a1 = 0.f, a2 = 0.f, a3 = 0.f;
        for (int k = 0; k < H; k += 4) {
            float4 hv = *(const float4*)&hs[cur][k];
            a0 += dot4(*(const float4*)(wr0 + k), hv);
            a1 += dot4(*(const float4*)(wr1 + k), hv);
            a2 += dot4(*(const float4*)(wr2 + k), hv);
            a3 += dot4(*(const float4*)(wr3 + k), hv);
        }
        float c = sigf(a1 + p1) * cst + sigf(a0 + p0) * tanh_fast(a2 + p2);
        float h = sigf(a3 + p3) * tanh_fast(c);
        cst = c;
        hs[cur ^ 1][j] = h;
        g_sl_h[(size_t)(b * S + t) * 256 + dir * H + j] = h;
        __syncthreads();
        cur ^= 1;
    }
}

// ============================================================
// K5: document attention pool, SINGLE-PASS (51.2 KB LDS). grid B, 128 thr.
// ============================================================
template <int T>
__global__ __launch_bounds__(128) void k_attn_pool_doc(
    const int* __restrict__ ids,
    const float* __restrict__ W1, const float* __restrict__ b1,
    const float* __restrict__ W2, const float* __restrict__ b2)
{
    constexpr int TH = T / 2;
    const int n = blockIdx.x;
    __shared__ float hsh[T][256];
    __shared__ float wsh[T];
    const int tid = threadIdx.x;
    const int lane = tid & 63;
    const int wv   = tid >> 6;

    const float* src = g_sl_h + (size_t)n * T * 256;
    for (int i = tid * 4; i < T * 256; i += 512)
        *(float4*)&(&hsh[0][0])[i] = *(const float4*)&src[i];
    __syncthreads();

    const int j0 = lane, j1 = lane + 64;
    const int tbase = wv * TH;
    float acc0[TH], acc1[TH];
    #pragma unroll
    for (int u = 0; u < TH; ++u) { acc0[u] = 0.f; acc1[u] = 0.f; }
    const float* w1a = &W1[j0 * 256];
    const float* w1b = &W1[j1 * 256];
    for (int k = 0; k < 256; k += 4) {
        float4 wa = *(const float4*)(w1a + k);
        float4 wb = *(const float4*)(w1b + k);
        #pragma unroll
        for (int u = 0; u < TH; ++u) {
            float4 hv = *(const float4*)&hsh[tbase + u][k];
            acc0[u] += dot4(wa, hv);
            acc1[u] += dot4(wb, hv);
        }
    }
    const float b1a = b1[j0], b1b = b1[j1];
    const float w2a = W2[j0], w2b = W2[j1];
    #pragma unroll
    for (int u = 0; u < TH; ++u) {
        float v = w2a * tanh_fast(acc0[u] + b1a) + w2b * tanh_fast(acc1[u] + b1b);
        #pragma unroll
        for (int off = 32; off > 0; off >>= 1) v += __shfl_down(v, off, 64);
        if (lane == 0) wsh[tbase + u] = v;
    }
    __syncthreads();

    if (tid < T) {
        bool valid = false;
        const int* ip = &ids[((size_t)n * T + tid) * W];
        for (int w = 0; w < W; ++w) valid |= (ip[w] != 0);
        wsh[tid] = valid ? (wsh[tid] + b2[0]) : -INFINITY;
    }
    __syncthreads();
    if (tid == 0) {
        float m = -INFINITY;
        for (int t = 0; t < T; ++t) m = fmaxf(m, wsh[t]);
        float sum = 0.f;
        for (int t = 0; t < T; ++t) sum += (wsh[t] == -INFINITY) ? 0.f : __expf(wsh[t] - m);
        const float inv = (sum > 0.f) ? 1.f / sum : 0.f;
        for (int t = 0; t < T; ++t) wsh[t] = (wsh[t] == -INFINITY) ? 0.f : __expf(wsh[t] - m) * inv;
    }
    __syncthreads();

    float o0 = 0.f, o1 = 0.f;
    #pragma unroll
    for (int t = 0; t < T; ++t) {
        float w = wsh[t];
        o0 += w * hsh[t][tid];
        o1 += w * hsh[t][tid + 128];
    }
    g_doc[(size_t)n * 256 + tid] = o0;
    g_doc[(size_t)n * 256 + tid + 128] = o1;
}

// ============================================================
// K6: classifier (fp32 out). grid B, 128 thr.
// ============================================================
__global__ __launch_bounds__(128) void k_classifier(
    const float* __restrict__ W1, const float* __restrict__ b1,
    const float* __restrict__ W2, const float* __restrict__ b2,
    float* __restrict__ out)
{
    const int b = blockIdx.x;
    __shared__ float dsh[256];
    __shared__ float hsh[128];
    const int tid = threadIdx.x;
    if (tid < 64) *(float4*)&dsh[tid * 4] = *(const float4*)&g_doc[(size_t)b * 256 + tid * 4];
    __syncthreads();
    float acc = 0.f;
    const float* w1p = &W1[tid * 256];
    for (int k = 0; k < 256; k += 4) {
        float4 w4 = *(const float4*)(w1p + k);
        float4 d4 = *(const float4*)&dsh[k];
        acc += dot4(w4, d4);
    }
    hsh[tid] = fmaxf(acc + b1[tid], 0.f);
    __syncthreads();
    if (tid < 3) {
        float a = b2[tid];
        const float* w2p = &W2[tid * 128];
        for (int j = 0; j < 128; ++j) a += w2p[j] * hsh[j];
        out[b * 3 + tid] = a;
    }
}

// ============================================================
extern "C" void kernel_launch(void* const* d_in, const int* in_sizes, int n_in,
                              void* d_out, int out_size, void* d_ws, size_t ws_size,
                              hipStream_t stream) {
    const int*   ids      = (const int*)d_in[0];
    const float* emb      = (const float*)d_in[1];
    const float* wl_Wih_f = (const float*)d_in[2];
    const float* wl_Whh_f = (const float*)d_in[3];
    const float* wl_bih_f = (const float*)d_in[4];
    const float* wl_bhh_f = (const float*)d_in[5];
    const float* wl_Wih_b = (const float*)d_in[6];
    const float* wl_Whh_b = (const float*)d_in[7];
    const float* wl_bih_b = (const float*)d_in[8];
    const float* wl_bhh_b = (const float*)d_in[9];
    const float* sl_Wih_f = (const float*)d_in[10];
    const float* sl_Whh_f = (const float*)d_in[11];
    const float* sl_bih_f = (const float*)d_in[12];
    const float* sl_bhh_f = (const float*)d_in[13];
    const float* sl_Wih_b = (const float*)d_in[14];
    const float* sl_Whh_b = (const float*)d_in[15];
    const float* sl_bih_b = (const float*)d_in[16];
    const float* sl_bhh_b = (const float*)d_in[17];
    const float* wa_W1 = (const float*)d_in[18];
    const float* wa_b1 = (const float*)d_in[19];
    const float* wa_W2 = (const float*)d_in[20];
    const float* wa_b2 = (const float*)d_in[21];
    const float* sa_W1 = (const float*)d_in[22];
    const float* sa_b1 = (const float*)d_in[23];
    const float* sa_W2 = (const float*)d_in[24];
    const float* sa_b2 = (const float*)d_in[25];
    const float* cl_W1 = (const float*)d_in[26];
    const float* cl_b1 = (const float*)d_in[27];
    const float* cl_W2 = (const float*)d_in[28];
    const float* cl_b2 = (const float*)d_in[29];

    k_emb_proj<<<(V / 16) * 2, 256, 0, stream>>>(
        emb, wl_Wih_f, wl_bih_f, wl_bhh_f, wl_Wih_b, wl_bih_b, wl_bhh_b);

    k_word_lstm<<<NW / NSEQ_W * 2, 512, 0, stream>>>(ids, wl_Whh_f, wl_Whh_b);

    k_attn_pool_word<W><<<NW, 128, 0, stream>>>(ids, wa_W1, wa_b1, wa_W2, wa_b2);

    k_sl_gin<<<NW / NSEQ_G * 2, 256, 0, stream>>>(
        sl_Wih_f, sl_bih_f, sl_bhh_f, sl_Wih_b, sl_bih_b, sl_bhh_b);

    k_sent_lstm<<<B * 2, 128, 0, stream>>>(sl_Whh_f, sl_Whh_b);

    k_attn_pool_doc<S><<<B, 128, 0, stream>>>(ids, sa_W1, sa_b1, sa_W2, sa_b2);

    k_classifier<<<B, 128, 0, stream>>>(cl_W1, cl_b1, cl_W2, cl_b2, (float*)d_out);
}

// Round 11
// 1191.054 us; speedup vs baseline: 2.6014x; 1.8571x over previous
//
#include <hip/hip_runtime.h>
#include <math.h>

typedef unsigned short ushort_t;
typedef __attribute__((ext_vector_type(8))) short short8;
typedef __attribute__((ext_vector_type(4))) float f32x4;

// ---- dims ----
constexpr int B  = 64;
constexpr int S  = 50;
constexpr int W  = 30;
constexpr int E  = 128;
constexpr int H  = 128;
constexpr int NW = B * S;      // 3200 word sequences
constexpr int V  = 50000;      // vocab
constexpr int MT = 16;         // word seqs per block (MFMA M-tile)
constexpr int NSEQ_G = 8;      // rows per block in sl gin GEMM

// ---- intermediates as module-scope device globals ----
__device__ float g_P    [(size_t)2 * V * 512];   // 204.8 MB: emb@Wih^T + biases, per dir
__device__ float g_wl_h [(size_t)NW * W * 256];  // 98.3 MB
__device__ float g_sent [(size_t)NW * 256];      // 3.28 MB
__device__ float g_gin_f[(size_t)NW * 512];      // 6.55 MB
__device__ float g_gin_b[(size_t)NW * 512];      // 6.55 MB
__device__ float g_sl_h [(size_t)B * S * 256];   // 3.28 MB
__device__ float g_doc  [(size_t)B * 256];       // 64 KB

// ---- helpers ----
__device__ __forceinline__ float sigf(float x) { return 1.0f / (1.0f + __expf(-x)); }
__device__ __forceinline__ float tanh_fast(float x) { return 2.0f / (1.0f + __expf(-2.0f * x)) - 1.0f; }
__device__ __forceinline__ float dot4(float4 a, float4 b) {
    return fmaf(a.x, b.x, fmaf(a.y, b.y, fmaf(a.z, b.z, a.w * b.w)));
}
__device__ __forceinline__ float bf2f(ushort_t u) {
    union { float f; unsigned int i; } v; v.i = ((unsigned int)u) << 16; return v.f;
}
__device__ __forceinline__ ushort_t f2bf(float f) {
    union { float f; unsigned int i; } v; v.f = f;
    unsigned int r = v.i + 0x7fffu + ((v.i >> 16) & 1u);
    return (ushort_t)(r >> 16);
}

// ============================================================
// K0: vocab input projection: P[dir][v][512] = emb[v]@Wih^T + bih + bhh.
// 16 rows/block. grid 6250, 256 thr. (unchanged)
// ============================================================
__global__ __launch_bounds__(256) void k_emb_proj(
    const float* __restrict__ emb,
    const float* __restrict__ Wih_f, const float* __restrict__ bih_f, const float* __restrict__ bhh_f,
    const float* __restrict__ Wih_b, const float* __restrict__ bih_b, const float* __restrict__ bhh_b)
{
    const int dir = blockIdx.x & 1;
    const int r0  = (blockIdx.x >> 1) * 16;
    const float* Wih = dir ? Wih_b : Wih_f;
    const float* bih = dir ? bih_b : bih_f;
    const float* bhh = dir ? bhh_b : bhh_f;

    __shared__ float xs[16][E];   // 8 KB
    const int tid = threadIdx.x;
    for (int i = tid * 4; i < 16 * E; i += 1024)
        *(float4*)&(&xs[0][0])[i] = *(const float4*)&emb[(size_t)r0 * E + i];
    __syncthreads();

    const int g0 = tid, g1 = tid + 256;
    const float* w0 = &Wih[(size_t)g0 * E];
    const float* w1 = &Wih[(size_t)g1 * E];
    float acc0[16], acc1[16];
    #pragma unroll
    for (int r = 0; r < 16; ++r) { acc0[r] = 0.f; acc1[r] = 0.f; }
    for (int k = 0; k < E; k += 4) {
        float4 wa = *(const float4*)(w0 + k);
        float4 wb = *(const float4*)(w1 + k);
        #pragma unroll
        for (int r = 0; r < 16; ++r) {
            float4 xv = *(const float4*)&xs[r][k];
            acc0[r] += dot4(wa, xv);
            acc1[r] += dot4(wb, xv);
        }
    }
    const float bv0 = bih[g0] + bhh[g0];
    const float bv1 = bih[g1] + bhh[g1];
    float* P = g_P + (size_t)dir * V * 512;
    #pragma unroll
    for (int r = 0; r < 16; ++r) {
        P[(size_t)(r0 + r) * 512 + g0] = acc0[r] + bv0;
        P[(size_t)(r0 + r) * 512 + g1] = acc1[r] + bv1;
    }
}

// ============================================================
// K1: word BiLSTM recurrence via MFMA, split-bf16 (hi+lo) for
// near-fp32 accuracy. 512 thr = 8 waves; wave w owns output cols
// [64w,64w+64): B-frags (Whh hi/lo) persistent in VGPRs (32 frags).
// h kept as bf16 hi/lo in LDS (row stride 136 halfwords for even
// bank spread on ds_read_b128). Per step: 8 A-frag LDS reads,
// 48 MFMA, gate exchange via LDS, distributed cell update,
// P-row gathers prefetched at step top. 2 barriers/step.
// grid = (3200/16)*2 = 400 blocks. LDS ~43.5 KB.
// MFMA layouts (verified m89/m120): A[m=lane&15][k=quad*8+j],
// B[k=quad*8+j][n=lane&15], D: col=lane&15, row=quad*4+reg.
// ============================================================
__global__ __launch_bounds__(512, 2) void k_word_lstm(
    const int* __restrict__ ids,
    const float* __restrict__ Whh_f, const float* __restrict__ Whh_b)
{
    const int dir = blockIdx.x & 1;
    const int s0  = (blockIdx.x >> 1) * MT;
    const float* Whh = dir ? Whh_b : Whh_f;
    const float* Pp  = g_P + (size_t)dir * V * 512;

    __shared__ ushort_t sh_hhi[MT][136];   // 4.25 KB
    __shared__ ushort_t sh_hlo[MT][136];   // 4.25 KB
    __shared__ float    sh_g[MT][514];     // 32.9 KB gate exchange
    __shared__ int      ids_sh[MT * W];    // 1.9 KB

    const int tid  = threadIdx.x;
    const int wv   = tid >> 6;       // wave 0..7
    const int lane = tid & 63;
    const int l15  = lane & 15;
    const int q    = lane >> 4;      // quad 0..3
    const int j    = tid & 127;      // cell index for epilogue
    const int sgrp = tid >> 7;       // 0..3

    // ---- persistent B-frags: Whh rows (output col n), split hi/lo ----
    // b_frag[nt][kt][i] = Whh[n][kt*32 + q*8 + i], n = wv*64 + nt*16 + l15
    short8 bhi[4][4], blo[4][4];
    #pragma unroll
    for (int nt = 0; nt < 4; ++nt) {
        const float* wrow = Whh + (size_t)(wv * 64 + nt * 16 + l15) * H;
        #pragma unroll
        for (int kt = 0; kt < 4; ++kt) {
            const float* wp = wrow + kt * 32 + q * 8;
            short8 h8, l8;
            #pragma unroll
            for (int i = 0; i < 8; ++i) {
                float f = wp[i];
                ushort_t hb = f2bf(f);
                h8[i] = (short)hb;
                l8[i] = (short)f2bf(f - bf2f(hb));
            }
            bhi[nt][kt] = h8;
            blo[nt][kt] = l8;
        }
    }

    for (int i = tid; i < MT * W; i += 512) ids_sh[i] = ids[s0 * W + i];
    for (int i = tid; i < MT * 136; i += 512) { (&sh_hhi[0][0])[i] = 0; (&sh_hlo[0][0])[i] = 0; }

    float cst[4] = {0.f, 0.f, 0.f, 0.f};   // c-state for seqs sgrp*4+r
    __syncthreads();

    for (int st = 0; st < W; ++st) {
        const int t = dir ? (W - 1 - st) : st;

        // prefetch P gate pre-activations (consumed after barrier 1)
        float pg[4][4];
        #pragma unroll
        for (int r = 0; r < 4; ++r) {
            const int s = sgrp * 4 + r;
            const float* Pr = Pp + (size_t)ids_sh[s * W + t] * 512 + j;
            #pragma unroll
            for (int g = 0; g < 4; ++g) pg[r][g] = Pr[g * 128];
        }

        // A-frags from LDS (hi/lo), 16B aligned
        short8 ahi[4], alo[4];
        {
            const ushort_t* ph = &sh_hhi[l15][q * 8];
            const ushort_t* pl = &sh_hlo[l15][q * 8];
            #pragma unroll
            for (int kt = 0; kt < 4; ++kt) {
                ahi[kt] = *(const short8*)(ph + kt * 32);
                alo[kt] = *(const short8*)(pl + kt * 32);
            }
        }

        f32x4 acc[4];
        #pragma unroll
        for (int nt = 0; nt < 4; ++nt) acc[nt] = (f32x4){0.f, 0.f, 0.f, 0.f};
        #pragma unroll
        for (int kt = 0; kt < 4; ++kt) {
            #pragma unroll
            for (int nt = 0; nt < 4; ++nt) {
                acc[nt] = __builtin_amdgcn_mfma_f32_16x16x32_bf16(ahi[kt], bhi[nt][kt], acc[nt], 0, 0, 0);
                acc[nt] = __builtin_amdgcn_mfma_f32_16x16x32_bf16(alo[kt], bhi[nt][kt], acc[nt], 0, 0, 0);
                acc[nt] = __builtin_amdgcn_mfma_f32_16x16x32_bf16(ahi[kt], blo[nt][kt], acc[nt], 0, 0, 0);
            }
        }

        // gate exchange: D row m = q*4+r (seq), col n = wv*64+nt*16+l15
        #pragma unroll
        for (int nt = 0; nt < 4; ++nt) {
            #pragma unroll
            for (int r = 0; r < 4; ++r)
                sh_g[q * 4 + r][wv * 64 + nt * 16 + l15] = acc[nt][r];
        }
        __syncthreads();

        // distributed cell update: thread handles cells (s = sgrp*4+r, j)
        #pragma unroll
        for (int r = 0; r < 4; ++r) {
            const int s = sgrp * 4 + r;
            float gi = sh_g[s][j      ] + pg[r][0];
            float gf = sh_g[s][j + 128] + pg[r][1];
            float gg = sh_g[s][j + 256] + pg[r][2];
            float go = sh_g[s][j + 384] + pg[r][3];
            float c = sigf(gf) * cst[r] + sigf(gi) * tanh_fast(gg);
            float h = sigf(go) * tanh_fast(c);
            cst[r] = c;
            g_wl_h[((size_t)(s0 + s) * W + t) * 256 + dir * H + j] = h;
            ushort_t hb = f2bf(h);
            sh_hhi[s][j] = hb;
            sh_hlo[s][j] = f2bf(h - bf2f(hb));
        }
        __syncthreads();
    }
}

// ============================================================
// K2: word attention pool, SINGLE-PASS (30.7 KB LDS). grid NW, 128 thr.
// ============================================================
template <int T>
__global__ __launch_bounds__(128) void k_attn_pool_word(
    const int* __restrict__ ids,
    const float* __restrict__ W1, const float* __restrict__ b1,
    const float* __restrict__ W2, const float* __restrict__ b2)
{
    constexpr int TH = T / 2;
    const int n = blockIdx.x;
    __shared__ float hsh[T][256];
    __shared__ float wsh[T];
    const int tid = threadIdx.x;
    const int lane = tid & 63;
    const int wv   = tid >> 6;

    const float* src = g_wl_h + (size_t)n * T * 256;
    for (int i = tid * 4; i < T * 256; i += 512)
        *(float4*)&(&hsh[0][0])[i] = *(const float4*)&src[i];
    __syncthreads();

    const int j0 = lane, j1 = lane + 64;
    const int tbase = wv * TH;
    float acc0[TH], acc1[TH];
    #pragma unroll
    for (int u = 0; u < TH; ++u) { acc0[u] = 0.f; acc1[u] = 0.f; }
    const float* w1a = &W1[j0 * 256];
    const float* w1b = &W1[j1 * 256];
    for (int k = 0; k < 256; k += 4) {
        float4 wa = *(const float4*)(w1a + k);
        float4 wb = *(const float4*)(w1b + k);
        #pragma unroll
        for (int u = 0; u < TH; ++u) {
            float4 hv = *(const float4*)&hsh[tbase + u][k];
            acc0[u] += dot4(wa, hv);
            acc1[u] += dot4(wb, hv);
        }
    }
    const float b1a = b1[j0], b1b = b1[j1];
    const float w2a = W2[j0], w2b = W2[j1];
    #pragma unroll
    for (int u = 0; u < TH; ++u) {
        float v = w2a * tanh_fast(acc0[u] + b1a) + w2b * tanh_fast(acc1[u] + b1b);
        #pragma unroll
        for (int off = 32; off > 0; off >>= 1) v += __shfl_down(v, off, 64);
        if (lane == 0) wsh[tbase + u] = v;
    }
    __syncthreads();

    if (tid < T) {
        bool valid = (ids[n * T + tid] != 0);
        wsh[tid] = valid ? (wsh[tid] + b2[0]) : -INFINITY;
    }
    __syncthreads();
    if (tid == 0) {
        float m = -INFINITY;
        for (int t = 0; t < T; ++t) m = fmaxf(m, wsh[t]);
        float sum = 0.f;
        for (int t = 0; t < T; ++t) sum += (wsh[t] == -INFINITY) ? 0.f : __expf(wsh[t] - m);
        const float inv = (sum > 0.f) ? 1.f / sum : 0.f;
        for (int t = 0; t < T; ++t) wsh[t] = (wsh[t] == -INFINITY) ? 0.f : __expf(wsh[t] - m) * inv;
    }
    __syncthreads();

    float o0 = 0.f, o1 = 0.f;
    #pragma unroll
    for (int t = 0; t < T; ++t) {
        float w = wsh[t];
        o0 += w * hsh[t][tid];
        o1 += w * hsh[t][tid + 128];
    }
    g_sent[(size_t)n * 256 + tid] = o0;
    g_sent[(size_t)n * 256 + tid + 128] = o1;
}

// ============================================================
// K3: sentence LSTM input projection. grid 800, 256 thr.
// ============================================================
__global__ __launch_bounds__(256) void k_sl_gin(
    const float* __restrict__ Wih_f, const float* __restrict__ bih_f, const float* __restrict__ bhh_f,
    const float* __restrict__ Wih_b, const float* __restrict__ bih_b, const float* __restrict__ bhh_b)
{
    const int dir = blockIdx.x & 1;
    const float* Wih = dir ? Wih_b : Wih_f;
    const float* bih = dir ? bih_b : bih_f;
    const float* bhh = dir ? bhh_b : bhh_f;
    float* gin = dir ? g_gin_b : g_gin_f;
    const int r0 = (blockIdx.x >> 1) * NSEQ_G;

    __shared__ float xs[NSEQ_G][256];
    const int tid = threadIdx.x;
    for (int i = tid * 4; i < NSEQ_G * 256; i += 1024)
        *(float4*)&(&xs[0][0])[i] = *(const float4*)&g_sent[(size_t)r0 * 256 + i];
    __syncthreads();

    const int g0 = tid, g1 = tid + 256;
    float acc0[NSEQ_G], acc1[NSEQ_G];
    #pragma unroll
    for (int s = 0; s < NSEQ_G; ++s) { acc0[s] = 0.f; acc1[s] = 0.f; }
    const float* w0 = &Wih[g0 * 256]; const float* w1 = &Wih[g1 * 256];
    for (int k = 0; k < 256; k += 4) {
        float4 wa = *(const float4*)(w0 + k);
        float4 wb = *(const float4*)(w1 + k);
        #pragma unroll
        for (int s = 0; s < NSEQ_G; ++s) {
            float4 xv = *(const float4*)&xs[s][k];
            acc0[s] += dot4(wa, xv);
            acc1[s] += dot4(wb, xv);
        }
    }
    const float bv0 = bih[g0] + bhh[g0];
    const float bv1 = bih[g1] + bhh[g1];
    #pragma unroll
    for (int s = 0; s < NSEQ_G; ++s) {
        gin[(size_t)(r0 + s) * 512 + g0] = acc0[s] + bv0;
        gin[(size_t)(r0 + s) * 512 + g1] = acc1[s] + bv1;
    }
}

// ============================================================
// K4: sentence BiLSTM, owns-cell, 1 seq/block. grid 128, 128 thr.
// ============================================================
__global__ __launch_bounds__(128) void k_sent_lstm(
    const float* __restrict__ Whh_f, const float* __restrict__ Whh_b)
{
    const int dir = blockIdx.x & 1;
    const int b   = blockIdx.x >> 1;
    const float* Whh = dir ? Whh_b : Whh_f;
    const float* gin = dir ? g_gin_b : g_gin_f;

    __shared__ float hs[2][H];
    const int j = threadIdx.x;
    const float* wr0 = Whh + (size_t)(j      ) * H;
    const float* wr1 = Whh + (size_t)(j + 128) * H;
    const float* wr2 = Whh + (size_t)(j + 256) * H;
    const float* wr3 = Whh + (size_t)(j + 384) * H;

    hs[0][j] = 0.f;
    float cst = 0.f;
    __syncthreads();

    int cur = 0;
    for (int st = 0; st < S; ++st) {
        const int t = dir ? (S - 1 - st) : st;
        const float* gp = gin + (size_t)(b * S + t) * 512;
        float p0 = gp[j], p1 = gp[j + 128], p2 = gp[j + 256], p3 = gp[j + 384];

        float a0 = 0.f, a1 = 0.f, a2 = 0.f, a3 = 0.f;
        for (int k = 0; k < H; k += 4) {
            float4 hv = *(const float4*)&hs[cur][k];
            a0 += dot4(*(const float4*)(wr0 + k), hv);
            a1 += dot4(*(const float4*)(wr1 + k), hv);
            a2 += dot4(*(const float4*)(wr2 + k), hv);
            a3 += dot4(*(const float4*)(wr3 + k), hv);
        }
        float c = sigf(a1 + p1) * cst + sigf(a0 + p0) * tanh_fast(a2 + p2);
        float h = sigf(a3 + p3) * tanh_fast(c);
        cst = c;
        hs[cur ^ 1][j] = h;
        g_sl_h[(size_t)(b * S + t) * 256 + dir * H + j] = h;
        __syncthreads();
        cur ^= 1;
    }
}

// ============================================================
// K5: document attention pool, SINGLE-PASS (51.2 KB LDS). grid B, 128 thr.
// ============================================================
template <int T>
__global__ __launch_bounds__(128) void k_attn_pool_doc(
    const int* __restrict__ ids,
    const float* __restrict__ W1, const float* __restrict__ b1,
    const float* __restrict__ W2, const float* __restrict__ b2)
{
    constexpr int TH = T / 2;
    const int n = blockIdx.x;
    __shared__ float hsh[T][256];
    __shared__ float wsh[T];
    const int tid = threadIdx.x;
    const int lane = tid & 63;
    const int wv   = tid >> 6;

    const float* src = g_sl_h + (size_t)n * T * 256;
    for (int i = tid * 4; i < T * 256; i += 512)
        *(float4*)&(&hsh[0][0])[i] = *(const float4*)&src[i];
    __syncthreads();

    const int j0 = lane, j1 = lane + 64;
    const int tbase = wv * TH;
    float acc0[TH], acc1[TH];
    #pragma unroll
    for (int u = 0; u < TH; ++u) { acc0[u] = 0.f; acc1[u] = 0.f; }
    const float* w1a = &W1[j0 * 256];
    const float* w1b = &W1[j1 * 256];
    for (int k = 0; k < 256; k += 4) {
        float4 wa = *(const float4*)(w1a + k);
        float4 wb = *(const float4*)(w1b + k);
        #pragma unroll
        for (int u = 0; u < TH; ++u) {
            float4 hv = *(const float4*)&hsh[tbase + u][k];
            acc0[u] += dot4(wa, hv);
            acc1[u] += dot4(wb, hv);
        }
    }
    const float b1a = b1[j0], b1b = b1[j1];
    const float w2a = W2[j0], w2b = W2[j1];
    #pragma unroll
    for (int u = 0; u < TH; ++u) {
        float v = w2a * tanh_fast(acc0[u] + b1a) + w2b * tanh_fast(acc1[u] + b1b);
        #pragma unroll
        for (int off = 32; off > 0; off >>= 1) v += __shfl_down(v, off, 64);
        if (lane == 0) wsh[tbase + u] = v;
    }
    __syncthreads();

    if (tid < T) {
        bool valid = false;
        const int* ip = &ids[((size_t)n * T + tid) * W];
        for (int w = 0; w < W; ++w) valid |= (ip[w] != 0);
        wsh[tid] = valid ? (wsh[tid] + b2[0]) : -INFINITY;
    }
    __syncthreads();
    if (tid == 0) {
        float m = -INFINITY;
        for (int t = 0; t < T; ++t) m = fmaxf(m, wsh[t]);
        float sum = 0.f;
        for (int t = 0; t < T; ++t) sum += (wsh[t] == -INFINITY) ? 0.f : __expf(wsh[t] - m);
        const float inv = (sum > 0.f) ? 1.f / sum : 0.f;
        for (int t = 0; t < T; ++t) wsh[t] = (wsh[t] == -INFINITY) ? 0.f : __expf(wsh[t] - m) * inv;
    }
    __syncthreads();

    float o0 = 0.f, o1 = 0.f;
    #pragma unroll
    for (int t = 0; t < T; ++t) {
        float w = wsh[t];
        o0 += w * hsh[t][tid];
        o1 += w * hsh[t][tid + 128];
    }
    g_doc[(size_t)n * 256 + tid] = o0;
    g_doc[(size_t)n * 256 + tid + 128] = o1;
}

// ============================================================
// K6: classifier (fp32 out). grid B, 128 thr.
// ============================================================
__global__ __launch_bounds__(128) void k_classifier(
    const float* __restrict__ W1, const float* __restrict__ b1,
    const float* __restrict__ W2, const float* __restrict__ b2,
    float* __restrict__ out)
{
    const int b = blockIdx.x;
    __shared__ float dsh[256];
    __shared__ float hsh[128];
    const int tid = threadIdx.x;
    if (tid < 64) *(float4*)&dsh[tid * 4] = *(const float4*)&g_doc[(size_t)b * 256 + tid * 4];
    __syncthreads();
    float acc = 0.f;
    const float* w1p = &W1[tid * 256];
    for (int k = 0; k < 256; k += 4) {
        float4 w4 = *(const float4*)(w1p + k);
        float4 d4 = *(const float4*)&dsh[k];
        acc += dot4(w4, d4);
    }
    hsh[tid] = fmaxf(acc + b1[tid], 0.f);
    __syncthreads();
    if (tid < 3) {
        float a = b2[tid];
        const float* w2p = &W2[tid * 128];
        for (int j = 0; j < 128; ++j) a += w2p[j] * hsh[j];
        out[b * 3 + tid] = a;
    }
}

// ============================================================
extern "C" void kernel_launch(void* const* d_in, const int* in_sizes, int n_in,
                              void* d_out, int out_size, void* d_ws, size_t ws_size,
                              hipStream_t stream) {
    const int*   ids      = (const int*)d_in[0];
    const float* emb      = (const float*)d_in[1];
    const float* wl_Wih_f = (const float*)d_in[2];
    const float* wl_Whh_f = (const float*)d_in[3];
    const float* wl_bih_f = (const float*)d_in[4];
    const float* wl_bhh_f = (const float*)d_in[5];
    const float* wl_Wih_b = (const float*)d_in[6];
    const float* wl_Whh_b = (const float*)d_in[7];
    const float* wl_bih_b = (const float*)d_in[8];
    const float* wl_bhh_b = (const float*)d_in[9];
    const float* sl_Wih_f = (const float*)d_in[10];
    const float* sl_Whh_f = (const float*)d_in[11];
    const float* sl_bih_f = (const float*)d_in[12];
    const float* sl_bhh_f = (const float*)d_in[13];
    const float* sl_Wih_b = (const float*)d_in[14];
    const float* sl_Whh_b = (const float*)d_in[15];
    const float* sl_bih_b = (const float*)d_in[16];
    const float* sl_bhh_b = (const float*)d_in[17];
    const float* wa_W1 = (const float*)d_in[18];
    const float* wa_b1 = (const float*)d_in[19];
    const float* wa_W2 = (const float*)d_in[20];
    const float* wa_b2 = (const float*)d_in[21];
    const float* sa_W1 = (const float*)d_in[22];
    const float* sa_b1 = (const float*)d_in[23];
    const float* sa_W2 = (const float*)d_in[24];
    const float* sa_b2 = (const float*)d_in[25];
    const float* cl_W1 = (const float*)d_in[26];
    const float* cl_b1 = (const float*)d_in[27];
    const float* cl_W2 = (const float*)d_in[28];
    const float* cl_b2 = (const float*)d_in[29];

    k_emb_proj<<<(V / 16) * 2, 256, 0, stream>>>(
        emb, wl_Wih_f, wl_bih_f, wl_bhh_f, wl_Wih_b, wl_bih_b, wl_bhh_b);

    k_word_lstm<<<NW / MT * 2, 512, 0, stream>>>(ids, wl_Whh_f, wl_Whh_b);

    k_attn_pool_word<W><<<NW, 128, 0, stream>>>(ids, wa_W1, wa_b1, wa_W2, wa_b2);

    k_sl_gin<<<NW / NSEQ_G * 2, 256, 0, stream>>>(
        sl_Wih_f, sl_bih_f, sl_bhh_f, sl_Wih_b, sl_bih_b, sl_bhh_b);

    k_sent_lstm<<<B * 2, 128, 0, stream>>>(sl_Whh_f, sl_Whh_b);

    k_attn_pool_doc<S><<<B, 128, 0, stream>>>(ids, sa_W1, sa_b1, sa_W2, sa_b2);

    k_classifier<<<B, 128, 0, stream>>>(cl_W1, cl_b1, cl_W2, cl_b2, (float*)d_out);
}

// Round 12
// 971.572 us; speedup vs baseline: 3.1891x; 1.2259x over previous
//
#include <hip/hip_runtime.h>
#include <math.h>

typedef unsigned short ushort_t;
typedef __attribute__((ext_vector_type(8))) short short8;
typedef __attribute__((ext_vector_type(4))) float f32x4;

// ---- dims ----
constexpr int B  = 64;
constexpr int S  = 50;
constexpr int W  = 30;
constexpr int E  = 128;
constexpr int H  = 128;
constexpr int NW = B * S;      // 3200 word sequences
constexpr int V  = 50000;      // vocab
constexpr int MT = 16;         // word seqs per block (MFMA M-tile)
constexpr int NSEQ_G = 8;      // rows per block in sl gin GEMM
constexpr int EP_NB = 512;     // emb_proj blocks per dir (grid-stride)

// ---- intermediates as module-scope device globals ----
__device__ float g_P    [(size_t)2 * V * 512];   // 204.8 MB: emb@Wih^T + biases, per dir
__device__ float g_wl_h [(size_t)NW * W * 256];  // 98.3 MB
__device__ float g_sent [(size_t)NW * 256];      // 3.28 MB
__device__ float g_gin_f[(size_t)NW * 512];      // 6.55 MB
__device__ float g_gin_b[(size_t)NW * 512];      // 6.55 MB
__device__ float g_sl_h [(size_t)B * S * 256];   // 3.28 MB
__device__ float g_doc  [(size_t)B * 256];       // 64 KB

// ---- helpers ----
__device__ __forceinline__ float sigf(float x) { return 1.0f / (1.0f + __expf(-x)); }
__device__ __forceinline__ float tanh_fast(float x) { return 2.0f / (1.0f + __expf(-2.0f * x)) - 1.0f; }
__device__ __forceinline__ float dot4(float4 a, float4 b) {
    return fmaf(a.x, b.x, fmaf(a.y, b.y, fmaf(a.z, b.z, a.w * b.w)));
}
__device__ __forceinline__ float bf2f(ushort_t u) {
    union { float f; unsigned int i; } v; v.i = ((unsigned int)u) << 16; return v.f;
}
__device__ __forceinline__ ushort_t f2bf(float f) {
    union { float f; unsigned int i; } v; v.f = f;
    unsigned int r = v.i + 0x7fffu + ((v.i >> 16) & 1u);
    return (ushort_t)(r >> 16);
}

// ============================================================
// K0: vocab input projection via MFMA (split-bf16 3-pass):
// P[dir][v][512] = emb[v]@Wih^T + bih + bhh.
// 512 thr = 8 waves; wave wv owns output cols [64wv, 64wv+64) with
// Wih hi/lo B-frags persistent in VGPRs (converted once per block).
// Grid-stride over 16-row vocab tiles (3125 tiles/dir, EP_NB blocks/dir).
// Per tile: stage 16 emb rows -> LDS (row pad 132 floats: 2-way banks),
// A-frags hi/lo, 48 MFMA, D -> padded LDS, +bias, coalesced float4 out.
// ============================================================
__global__ __launch_bounds__(512, 2) void k_emb_proj(
    const float* __restrict__ emb,
    const float* __restrict__ Wih_f, const float* __restrict__ bih_f, const float* __restrict__ bhh_f,
    const float* __restrict__ Wih_b, const float* __restrict__ bih_b, const float* __restrict__ bhh_b)
{
    constexpr int NT = V / 16;   // 3125 tiles per dir
    const int dir = blockIdx.x & 1;
    const int bid = blockIdx.x >> 1;
    const float* Wih = dir ? Wih_b : Wih_f;
    const float* bih = dir ? bih_b : bih_f;
    const float* bhh = dir ? bhh_b : bhh_f;
    float* P = g_P + (size_t)dir * V * 512;

    const int tid  = threadIdx.x;
    const int wv   = tid >> 6;
    const int lane = tid & 63;
    const int l15  = lane & 15;
    const int q    = lane >> 4;

    // persistent B-frags: Wih row n = wv*64+nt*16+l15, k = kt*32+q*8+i
    short8 bhi[4][4], blo[4][4];
    #pragma unroll
    for (int nt = 0; nt < 4; ++nt) {
        const float* wrow = Wih + (size_t)(wv * 64 + nt * 16 + l15) * E;
        #pragma unroll
        for (int kt = 0; kt < 4; ++kt) {
            const float* wp = wrow + kt * 32 + q * 8;
            short8 h8, l8;
            #pragma unroll
            for (int i = 0; i < 8; ++i) {
                float f = wp[i];
                ushort_t hb = f2bf(f);
                h8[i] = (short)hb;
                l8[i] = (short)f2bf(f - bf2f(hb));
            }
            bhi[nt][kt] = h8;
            blo[nt][kt] = l8;
        }
    }

    // this thread's output columns (fixed across row iterations)
    const int wcol = (tid * 4) & 511;
    float4 bias4 = make_float4(bih[wcol] + bhh[wcol], bih[wcol + 1] + bhh[wcol + 1],
                               bih[wcol + 2] + bhh[wcol + 2], bih[wcol + 3] + bhh[wcol + 3]);

    __shared__ float xs[16][132];    // 8.4 KB, pad 132: rows shift 4 banks
    __shared__ float os[16][516];    // 33 KB, pad 516 keeps float4 align

    for (int tile = bid; tile < NT; tile += EP_NB) {
        const int r0 = tile * 16;
        // stage 16 emb rows, coalesced float4
        {
            const int i = tid * 4;          // 0..2047
            *(float4*)&xs[i >> 7][i & 127] = *(const float4*)&emb[(size_t)r0 * E + i];
        }
        __syncthreads();

        // A-frags hi/lo from xs: A[m=l15][k=kt*32+q*8+i]
        short8 ahi[4], alo[4];
        #pragma unroll
        for (int kt = 0; kt < 4; ++kt) {
            const float* xp = &xs[l15][kt * 32 + q * 8];
            short8 h8, l8;
            #pragma unroll
            for (int i = 0; i < 8; ++i) {
                float f = xp[i];
                ushort_t hb = f2bf(f);
                h8[i] = (short)hb;
                l8[i] = (short)f2bf(f - bf2f(hb));
            }
            ahi[kt] = h8;
            alo[kt] = l8;
        }

        f32x4 acc[4];
        #pragma unroll
        for (int nt = 0; nt < 4; ++nt) acc[nt] = (f32x4){0.f, 0.f, 0.f, 0.f};
        #pragma unroll
        for (int kt = 0; kt < 4; ++kt) {
            #pragma unroll
            for (int nt = 0; nt < 4; ++nt) {
                acc[nt] = __builtin_amdgcn_mfma_f32_16x16x32_bf16(ahi[kt], bhi[nt][kt], acc[nt], 0, 0, 0);
                acc[nt] = __builtin_amdgcn_mfma_f32_16x16x32_bf16(alo[kt], bhi[nt][kt], acc[nt], 0, 0, 0);
                acc[nt] = __builtin_amdgcn_mfma_f32_16x16x32_bf16(ahi[kt], blo[nt][kt], acc[nt], 0, 0, 0);
            }
        }

        // D -> os: row m = q*4+r (vocab row in tile), col n = wv*64+nt*16+l15
        #pragma unroll
        for (int nt = 0; nt < 4; ++nt) {
            #pragma unroll
            for (int r = 0; r < 4; ++r)
                os[q * 4 + r][wv * 64 + nt * 16 + l15] = acc[nt][r];
        }
        __syncthreads();

        // coalesced write with bias
        #pragma unroll
        for (int i = tid * 4; i < 16 * 512; i += 2048) {
            const int row = i >> 9, col = i & 511;
            float4 v = *(const float4*)&os[row][col];
            v.x += bias4.x; v.y += bias4.y; v.z += bias4.z; v.w += bias4.w;
            *(float4*)&P[(size_t)(r0 + row) * 512 + col] = v;
        }
        __syncthreads();
    }
}

// ============================================================
// K1: word BiLSTM recurrence via MFMA, split-bf16 (hi+lo).
// (unchanged from R11 — verified absmax 0.0)
// ============================================================
__global__ __launch_bounds__(512, 2) void k_word_lstm(
    const int* __restrict__ ids,
    const float* __restrict__ Whh_f, const float* __restrict__ Whh_b)
{
    const int dir = blockIdx.x & 1;
    const int s0  = (blockIdx.x >> 1) * MT;
    const float* Whh = dir ? Whh_b : Whh_f;
    const float* Pp  = g_P + (size_t)dir * V * 512;

    __shared__ ushort_t sh_hhi[MT][136];
    __shared__ ushort_t sh_hlo[MT][136];
    __shared__ float    sh_g[MT][514];
    __shared__ int      ids_sh[MT * W];

    const int tid  = threadIdx.x;
    const int wv   = tid >> 6;
    const int lane = tid & 63;
    const int l15  = lane & 15;
    const int q    = lane >> 4;
    const int j    = tid & 127;
    const int sgrp = tid >> 7;

    short8 bhi[4][4], blo[4][4];
    #pragma unroll
    for (int nt = 0; nt < 4; ++nt) {
        const float* wrow = Whh + (size_t)(wv * 64 + nt * 16 + l15) * H;
        #pragma unroll
        for (int kt = 0; kt < 4; ++kt) {
            const float* wp = wrow + kt * 32 + q * 8;
            short8 h8, l8;
            #pragma unroll
            for (int i = 0; i < 8; ++i) {
                float f = wp[i];
                ushort_t hb = f2bf(f);
                h8[i] = (short)hb;
                l8[i] = (short)f2bf(f - bf2f(hb));
            }
            bhi[nt][kt] = h8;
            blo[nt][kt] = l8;
        }
    }

    for (int i = tid; i < MT * W; i += 512) ids_sh[i] = ids[s0 * W + i];
    for (int i = tid; i < MT * 136; i += 512) { (&sh_hhi[0][0])[i] = 0; (&sh_hlo[0][0])[i] = 0; }

    float cst[4] = {0.f, 0.f, 0.f, 0.f};
    __syncthreads();

    for (int st = 0; st < W; ++st) {
        const int t = dir ? (W - 1 - st) : st;

        float pg[4][4];
        #pragma unroll
        for (int r = 0; r < 4; ++r) {
            const int s = sgrp * 4 + r;
            const float* Pr = Pp + (size_t)ids_sh[s * W + t] * 512 + j;
            #pragma unroll
            for (int g = 0; g < 4; ++g) pg[r][g] = Pr[g * 128];
        }

        short8 ahi[4], alo[4];
        {
            const ushort_t* ph = &sh_hhi[l15][q * 8];
            const ushort_t* pl = &sh_hlo[l15][q * 8];
            #pragma unroll
            for (int kt = 0; kt < 4; ++kt) {
                ahi[kt] = *(const short8*)(ph + kt * 32);
                alo[kt] = *(const short8*)(pl + kt * 32);
            }
        }

        f32x4 acc[4];
        #pragma unroll
        for (int nt = 0; nt < 4; ++nt) acc[nt] = (f32x4){0.f, 0.f, 0.f, 0.f};
        #pragma unroll
        for (int kt = 0; kt < 4; ++kt) {
            #pragma unroll
            for (int nt = 0; nt < 4; ++nt) {
                acc[nt] = __builtin_amdgcn_mfma_f32_16x16x32_bf16(ahi[kt], bhi[nt][kt], acc[nt], 0, 0, 0);
                acc[nt] = __builtin_amdgcn_mfma_f32_16x16x32_bf16(alo[kt], bhi[nt][kt], acc[nt], 0, 0, 0);
                acc[nt] = __builtin_amdgcn_mfma_f32_16x16x32_bf16(ahi[kt], blo[nt][kt], acc[nt], 0, 0, 0);
            }
        }

        #pragma unroll
        for (int nt = 0; nt < 4; ++nt) {
            #pragma unroll
            for (int r = 0; r < 4; ++r)
                sh_g[q * 4 + r][wv * 64 + nt * 16 + l15] = acc[nt][r];
        }
        __syncthreads();

        #pragma unroll
        for (int r = 0; r < 4; ++r) {
            const int s = sgrp * 4 + r;
            float gi = sh_g[s][j      ] + pg[r][0];
            float gf = sh_g[s][j + 128] + pg[r][1];
            float gg = sh_g[s][j + 256] + pg[r][2];
            float go = sh_g[s][j + 384] + pg[r][3];
            float c = sigf(gf) * cst[r] + sigf(gi) * tanh_fast(gg);
            float h = sigf(go) * tanh_fast(c);
            cst[r] = c;
            g_wl_h[((size_t)(s0 + s) * W + t) * 256 + dir * H + j] = h;
            ushort_t hb = f2bf(h);
            sh_hhi[s][j] = hb;
            sh_hlo[s][j] = f2bf(h - bf2f(hb));
        }
        __syncthreads();
    }
}

// ============================================================
// K2: word attention pool, SINGLE-PASS (30.7 KB LDS). grid NW, 128 thr.
// ============================================================
template <int T>
__global__ __launch_bounds__(128) void k_attn_pool_word(
    const int* __restrict__ ids,
    const float* __restrict__ W1, const float* __restrict__ b1,
    const float* __restrict__ W2, const float* __restrict__ b2)
{
    constexpr int TH = T / 2;
    const int n = blockIdx.x;
    __shared__ float hsh[T][256];
    __shared__ float wsh[T];
    const int tid = threadIdx.x;
    const int lane = tid & 63;
    const int wv   = tid >> 6;

    const float* src = g_wl_h + (size_t)n * T * 256;
    for (int i = tid * 4; i < T * 256; i += 512)
        *(float4*)&(&hsh[0][0])[i] = *(const float4*)&src[i];
    __syncthreads();

    const int j0 = lane, j1 = lane + 64;
    const int tbase = wv * TH;
    float acc0[TH], acc1[TH];
    #pragma unroll
    for (int u = 0; u < TH; ++u) { acc0[u] = 0.f; acc1[u] = 0.f; }
    const float* w1a = &W1[j0 * 256];
    const float* w1b = &W1[j1 * 256];
    for (int k = 0; k < 256; k += 4) {
        float4 wa = *(const float4*)(w1a + k);
        float4 wb = *(const float4*)(w1b + k);
        #pragma unroll
        for (int u = 0; u < TH; ++u) {
            float4 hv = *(const float4*)&hsh[tbase + u][k];
            acc0[u] += dot4(wa, hv);
            acc1[u] += dot4(wb, hv);
        }
    }
    const float b1a = b1[j0], b1b = b1[j1];
    const float w2a = W2[j0], w2b = W2[j1];
    #pragma unroll
    for (int u = 0; u < TH; ++u) {
        float v = w2a * tanh_fast(acc0[u] + b1a) + w2b * tanh_fast(acc1[u] + b1b);
        #pragma unroll
        for (int off = 32; off > 0; off >>= 1) v += __shfl_down(v, off, 64);
        if (lane == 0) wsh[tbase + u] = v;
    }
    __syncthreads();

    if (tid < T) {
        bool valid = (ids[n * T + tid] != 0);
        wsh[tid] = valid ? (wsh[tid] + b2[0]) : -INFINITY;
    }
    __syncthreads();
    if (tid == 0) {
        float m = -INFINITY;
        for (int t = 0; t < T; ++t) m = fmaxf(m, wsh[t]);
        float sum = 0.f;
        for (int t = 0; t < T; ++t) sum += (wsh[t] == -INFINITY) ? 0.f : __expf(wsh[t] - m);
        const float inv = (sum > 0.f) ? 1.f / sum : 0.f;
        for (int t = 0; t < T; ++t) wsh[t] = (wsh[t] == -INFINITY) ? 0.f : __expf(wsh[t] - m) * inv;
    }
    __syncthreads();

    float o0 = 0.f, o1 = 0.f;
    #pragma unroll
    for (int t = 0; t < T; ++t) {
        float w = wsh[t];
        o0 += w * hsh[t][tid];
        o1 += w * hsh[t][tid + 128];
    }
    g_sent[(size_t)n * 256 + tid] = o0;
    g_sent[(size_t)n * 256 + tid + 128] = o1;
}

// ============================================================
// K3: sentence LSTM input projection. grid 800, 256 thr.
// ============================================================
__global__ __launch_bounds__(256) void k_sl_gin(
    const float* __restrict__ Wih_f, const float* __restrict__ bih_f, const float* __restrict__ bhh_f,
    const float* __restrict__ Wih_b, const float* __restrict__ bih_b, const float* __restrict__ bhh_b)
{
    const int dir = blockIdx.x & 1;
    const float* Wih = dir ? Wih_b : Wih_f;
    const float* bih = dir ? bih_b : bih_f;
    const float* bhh = dir ? bhh_b : bhh_f;
    float* gin = dir ? g_gin_b : g_gin_f;
    const int r0 = (blockIdx.x >> 1) * NSEQ_G;

    __shared__ float xs[NSEQ_G][256];
    const int tid = threadIdx.x;
    for (int i = tid * 4; i < NSEQ_G * 256; i += 1024)
        *(float4*)&(&xs[0][0])[i] = *(const float4*)&g_sent[(size_t)r0 * 256 + i];
    __syncthreads();

    const int g0 = tid, g1 = tid + 256;
    float acc0[NSEQ_G], acc1[NSEQ_G];
    #pragma unroll
    for (int s = 0; s < NSEQ_G; ++s) { acc0[s] = 0.f; acc1[s] = 0.f; }
    const float* w0 = &Wih[g0 * 256]; const float* w1 = &Wih[g1 * 256];
    for (int k = 0; k < 256; k += 4) {
        float4 wa = *(const float4*)(w0 + k);
        float4 wb = *(const float4*)(w1 + k);
        #pragma unroll
        for (int s = 0; s < NSEQ_G; ++s) {
            float4 xv = *(const float4*)&xs[s][k];
            acc0[s] += dot4(wa, xv);
            acc1[s] += dot4(wb, xv);
        }
    }
    const float bv0 = bih[g0] + bhh[g0];
    const float bv1 = bih[g1] + bhh[g1];
    #pragma unroll
    for (int s = 0; s < NSEQ_G; ++s) {
        gin[(size_t)(r0 + s) * 512 + g0] = acc0[s] + bv0;
        gin[(size_t)(r0 + s) * 512 + g1] = acc1[s] + bv1;
    }
}

// ============================================================
// K4: sentence BiLSTM, owns-cell, 1 seq/block. grid 128, 128 thr.
// ============================================================
__global__ __launch_bounds__(128) void k_sent_lstm(
    const float* __restrict__ Whh_f, const float* __restrict__ Whh_b)
{
    const int dir = blockIdx.x & 1;
    const int b   = blockIdx.x >> 1;
    const float* Whh = dir ? Whh_b : Whh_f;
    const float* gin = dir ? g_gin_b : g_gin_f;

    __shared__ float hs[2][H];
    const int j = threadIdx.x;
    const float* wr0 = Whh + (size_t)(j      ) * H;
    const float* wr1 = Whh + (size_t)(j + 128) * H;
    const float* wr2 = Whh + (size_t)(j + 256) * H;
    const float* wr3 = Whh + (size_t)(j + 384) * H;

    hs[0][j] = 0.f;
    float cst = 0.f;
    __syncthreads();

    int cur = 0;
    for (int st = 0; st < S; ++st) {
        const int t = dir ? (S - 1 - st) : st;
        const float* gp = gin + (size_t)(b * S + t) * 512;
        float p0 = gp[j], p1 = gp[j + 128], p2 = gp[j + 256], p3 = gp[j + 384];

        float a0 = 0.f, a1 = 0.f, a2 = 0.f, a3 = 0.f;
        for (int k = 0; k < H; k += 4) {
            float4 hv = *(const float4*)&hs[cur][k];
            a0 += dot4(*(const float4*)(wr0 + k), hv);
            a1 += dot4(*(const float4*)(wr1 + k), hv);
            a2 += dot4(*(const float4*)(wr2 + k), hv);
            a3 += dot4(*(const float4*)(wr3 + k), hv);
        }
        float c = sigf(a1 + p1) * cst + sigf(a0 + p0) * tanh_fast(a2 + p2);
        float h = sigf(a3 + p3) * tanh_fast(c);
        cst = c;
        hs[cur ^ 1][j] = h;
        g_sl_h[(size_t)(b * S + t) * 256 + dir * H + j] = h;
        __syncthreads();
        cur ^= 1;
    }
}

// ============================================================
// K5: document attention pool, SINGLE-PASS (51.2 KB LDS). grid B, 128 thr.
// ============================================================
template <int T>
__global__ __launch_bounds__(128) void k_attn_pool_doc(
    const int* __restrict__ ids,
    const float* __restrict__ W1, const float* __restrict__ b1,
    const float* __restrict__ W2, const float* __restrict__ b2)
{
    constexpr int TH = T / 2;
    const int n = blockIdx.x;
    __shared__ float hsh[T][256];
    __shared__ float wsh[T];
    const int tid = threadIdx.x;
    const int lane = tid & 63;
    const int wv   = tid >> 6;

    const float* src = g_sl_h + (size_t)n * T * 256;
    for (int i = tid * 4; i < T * 256; i += 512)
        *(float4*)&(&hsh[0][0])[i] = *(const float4*)&src[i];
    __syncthreads();

    const int j0 = lane, j1 = lane + 64;
    const int tbase = wv * TH;
    float acc0[TH], acc1[TH];
    #pragma unroll
    for (int u = 0; u < TH; ++u) { acc0[u] = 0.f; acc1[u] = 0.f; }
    const float* w1a = &W1[j0 * 256];
    const float* w1b = &W1[j1 * 256];
    for (int k = 0; k < 256; k += 4) {
        float4 wa = *(const float4*)(w1a + k);
        float4 wb = *(const float4*)(w1b + k);
        #pragma unroll
        for (int u = 0; u < TH; ++u) {
            float4 hv = *(const float4*)&hsh[tbase + u][k];
            acc0[u] += dot4(wa, hv);
            acc1[u] += dot4(wb, hv);
        }
    }
    const float b1a = b1[j0], b1b = b1[j1];
    const float w2a = W2[j0], w2b = W2[j1];
    #pragma unroll
    for (int u = 0; u < TH; ++u) {
        float v = w2a * tanh_fast(acc0[u] + b1a) + w2b * tanh_fast(acc1[u] + b1b);
        #pragma unroll
        for (int off = 32; off > 0; off >>= 1) v += __shfl_down(v, off, 64);
        if (lane == 0) wsh[tbase + u] = v;
    }
    __syncthreads();

    if (tid < T) {
        bool valid = false;
        const int* ip = &ids[((size_t)n * T + tid) * W];
        for (int w = 0; w < W; ++w) valid |= (ip[w] != 0);
        wsh[tid] = valid ? (wsh[tid] + b2[0]) : -INFINITY;
    }
    __syncthreads();
    if (tid == 0) {
        float m = -INFINITY;
        for (int t = 0; t < T; ++t) m = fmaxf(m, wsh[t]);
        float sum = 0.f;
        for (int t = 0; t < T; ++t) sum += (wsh[t] == -INFINITY) ? 0.f : __expf(wsh[t] - m);
        const float inv = (sum > 0.f) ? 1.f / sum : 0.f;
        for (int t = 0; t < T; ++t) wsh[t] = (wsh[t] == -INFINITY) ? 0.f : __expf(wsh[t] - m) * inv;
    }
    __syncthreads();

    float o0 = 0.f, o1 = 0.f;
    #pragma unroll
    for (int t = 0; t < T; ++t) {
        float w = wsh[t];
        o0 += w * hsh[t][tid];
        o1 += w * hsh[t][tid + 128];
    }
    g_doc[(size_t)n * 256 + tid] = o0;
    g_doc[(size_t)n * 256 + tid + 128] = o1;
}

// ============================================================
// K6: classifier (fp32 out). grid B, 128 thr.
// ============================================================
__global__ __launch_bounds__(128) void k_classifier(
    const float* __restrict__ W1, const float* __restrict__ b1,
    const float* __restrict__ W2, const float* __restrict__ b2,
    float* __restrict__ out)
{
    const int b = blockIdx.x;
    __shared__ float dsh[256];
    __shared__ float hsh[128];
    const int tid = threadIdx.x;
    if (tid < 64) *(float4*)&dsh[tid * 4] = *(const float4*)&g_doc[(size_t)b * 256 + tid * 4];
    __syncthreads();
    float acc = 0.f;
    const float* w1p = &W1[tid * 256];
    for (int k = 0; k < 256; k += 4) {
        float4 w4 = *(const float4*)(w1p + k);
        float4 d4 = *(const float4*)&dsh[k];
        acc += dot4(w4, d4);
    }
    hsh[tid] = fmaxf(acc + b1[tid], 0.f);
    __syncthreads();
    if (tid < 3) {
        float a = b2[tid];
        const float* w2p = &W2[tid * 128];
        for (int j = 0; j < 128; ++j) a += w2p[j] * hsh[j];
        out[b * 3 + tid] = a;
    }
}

// ============================================================
extern "C" void kernel_launch(void* const* d_in, const int* in_sizes, int n_in,
                              void* d_out, int out_size, void* d_ws, size_t ws_size,
                              hipStream_t stream) {
    const int*   ids      = (const int*)d_in[0];
    const float* emb      = (const float*)d_in[1];
    const float* wl_Wih_f = (const float*)d_in[2];
    const float* wl_Whh_f = (const float*)d_in[3];
    const float* wl_bih_f = (const float*)d_in[4];
    const float* wl_bhh_f = (const float*)d_in[5];
    const float* wl_Wih_b = (const float*)d_in[6];
    const float* wl_Whh_b = (const float*)d_in[7];
    const float* wl_bih_b = (const float*)d_in[8];
    const float* wl_bhh_b = (const float*)d_in[9];
    const float* sl_Wih_f = (const float*)d_in[10];
    const float* sl_Whh_f = (const float*)d_in[11];
    const float* sl_bih_f = (const float*)d_in[12];
    const float* sl_bhh_f = (const float*)d_in[13];
    const float* sl_Wih_b = (const float*)d_in[14];
    const float* sl_Whh_b = (const float*)d_in[15];
    const float* sl_bih_b = (const float*)d_in[16];
    const float* sl_bhh_b = (const float*)d_in[17];
    const float* wa_W1 = (const float*)d_in[18];
    const float* wa_b1 = (const float*)d_in[19];
    const float* wa_W2 = (const float*)d_in[20];
    const float* wa_b2 = (const float*)d_in[21];
    const float* sa_W1 = (const float*)d_in[22];
    const float* sa_b1 = (const float*)d_in[23];
    const float* sa_W2 = (const float*)d_in[24];
    const float* sa_b2 = (const float*)d_in[25];
    const float* cl_W1 = (const float*)d_in[26];
    const float* cl_b1 = (const float*)d_in[27];
    const float* cl_W2 = (const float*)d_in[28];
    const float* cl_b2 = (const float*)d_in[29];

    k_emb_proj<<<EP_NB * 2, 512, 0, stream>>>(
        emb, wl_Wih_f, wl_bih_f, wl_bhh_f, wl_Wih_b, wl_bih_b, wl_bhh_b);

    k_word_lstm<<<NW / MT * 2, 512, 0, stream>>>(ids, wl_Whh_f, wl_Whh_b);

    k_attn_pool_word<W><<<NW, 128, 0, stream>>>(ids, wa_W1, wa_b1, wa_W2, wa_b2);

    k_sl_gin<<<NW / NSEQ_G * 2, 256, 0, stream>>>(
        sl_Wih_f, sl_bih_f, sl_bhh_f, sl_Wih_b, sl_bih_b, sl_bhh_b);

    k_sent_lstm<<<B * 2, 128, 0, stream>>>(sl_Whh_f, sl_Whh_b);

    k_attn_pool_doc<S><<<B, 128, 0, stream>>>(ids, sa_W1, sa_b1, sa_W2, sa_b2);

    k_classifier<<<B, 128, 0, stream>>>(cl_W1, cl_b1, cl_W2, cl_b2, (float*)d_out);
}

// Round 13
// 878.329 us; speedup vs baseline: 3.5276x; 1.1062x over previous
//
#include <hip/hip_runtime.h>
#include <math.h>

typedef unsigned short ushort_t;
typedef __attribute__((ext_vector_type(8))) short short8;
typedef __attribute__((ext_vector_type(4))) float f32x4;

// ---- dims ----
constexpr int B  = 64;
constexpr int S  = 50;
constexpr int W  = 30;
constexpr int E  = 128;
constexpr int H  = 128;
constexpr int NW = B * S;      // 3200 word sequences
constexpr int V  = 50000;      // vocab
constexpr int MT = 16;         // word seqs per block (MFMA M-tile)
constexpr int NSEQ_G = 8;      // rows per block in sl gin GEMM
constexpr int EP_NB = 512;     // emb_proj blocks per dir (grid-stride)
constexpr int WS_NB = 1024;    // word_scores blocks (grid-stride)

// ---- intermediates as module-scope device globals ----
__device__ float g_P    [(size_t)2 * V * 512];   // 204.8 MB
__device__ float g_wl_h [(size_t)NW * W * 256];  // 98.3 MB
__device__ float g_wsc  [(size_t)NW * W];        // 384 KB word attn scores
__device__ float g_sent [(size_t)NW * 256];      // 3.28 MB
__device__ float g_gin_f[(size_t)NW * 512];      // 6.55 MB
__device__ float g_gin_b[(size_t)NW * 512];      // 6.55 MB
__device__ float g_sl_h [(size_t)B * S * 256];   // 3.28 MB
__device__ float g_doc  [(size_t)B * 256];       // 64 KB

// ---- helpers ----
__device__ __forceinline__ float sigf(float x) { return 1.0f / (1.0f + __expf(-x)); }
__device__ __forceinline__ float tanh_fast(float x) { return 2.0f / (1.0f + __expf(-2.0f * x)) - 1.0f; }
__device__ __forceinline__ float dot4(float4 a, float4 b) {
    return fmaf(a.x, b.x, fmaf(a.y, b.y, fmaf(a.z, b.z, a.w * b.w)));
}
__device__ __forceinline__ float bf2f(ushort_t u) {
    union { float f; unsigned int i; } v; v.i = ((unsigned int)u) << 16; return v.f;
}
__device__ __forceinline__ ushort_t f2bf(float f) {
    union { float f; unsigned int i; } v; v.f = f;
    unsigned int r = v.i + 0x7fffu + ((v.i >> 16) & 1u);
    return (ushort_t)(r >> 16);
}

// ============================================================
// K0: vocab input projection via MFMA (split-bf16 3-pass). Unchanged R12.
// ============================================================
__global__ __launch_bounds__(512, 2) void k_emb_proj(
    const float* __restrict__ emb,
    const float* __restrict__ Wih_f, const float* __restrict__ bih_f, const float* __restrict__ bhh_f,
    const float* __restrict__ Wih_b, const float* __restrict__ bih_b, const float* __restrict__ bhh_b)
{
    constexpr int NT = V / 16;
    const int dir = blockIdx.x & 1;
    const int bid = blockIdx.x >> 1;
    const float* Wih = dir ? Wih_b : Wih_f;
    const float* bih = dir ? bih_b : bih_f;
    const float* bhh = dir ? bhh_b : bhh_f;
    float* P = g_P + (size_t)dir * V * 512;

    const int tid  = threadIdx.x;
    const int wv   = tid >> 6;
    const int lane = tid & 63;
    const int l15  = lane & 15;
    const int q    = lane >> 4;

    short8 bhi[4][4], blo[4][4];
    #pragma unroll
    for (int nt = 0; nt < 4; ++nt) {
        const float* wrow = Wih + (size_t)(wv * 64 + nt * 16 + l15) * E;
        #pragma unroll
        for (int kt = 0; kt < 4; ++kt) {
            const float* wp = wrow + kt * 32 + q * 8;
            short8 h8, l8;
            #pragma unroll
            for (int i = 0; i < 8; ++i) {
                float f = wp[i];
                ushort_t hb = f2bf(f);
                h8[i] = (short)hb;
                l8[i] = (short)f2bf(f - bf2f(hb));
            }
            bhi[nt][kt] = h8;
            blo[nt][kt] = l8;
        }
    }

    const int wcol = (tid * 4) & 511;
    float4 bias4 = make_float4(bih[wcol] + bhh[wcol], bih[wcol + 1] + bhh[wcol + 1],
                               bih[wcol + 2] + bhh[wcol + 2], bih[wcol + 3] + bhh[wcol + 3]);

    __shared__ float xs[16][132];
    __shared__ float os[16][516];

    for (int tile = bid; tile < NT; tile += EP_NB) {
        const int r0 = tile * 16;
        {
            const int i = tid * 4;
            *(float4*)&xs[i >> 7][i & 127] = *(const float4*)&emb[(size_t)r0 * E + i];
        }
        __syncthreads();

        short8 ahi[4], alo[4];
        #pragma unroll
        for (int kt = 0; kt < 4; ++kt) {
            const float* xp = &xs[l15][kt * 32 + q * 8];
            short8 h8, l8;
            #pragma unroll
            for (int i = 0; i < 8; ++i) {
                float f = xp[i];
                ushort_t hb = f2bf(f);
                h8[i] = (short)hb;
                l8[i] = (short)f2bf(f - bf2f(hb));
            }
            ahi[kt] = h8;
            alo[kt] = l8;
        }

        f32x4 acc[4];
        #pragma unroll
        for (int nt = 0; nt < 4; ++nt) acc[nt] = (f32x4){0.f, 0.f, 0.f, 0.f};
        #pragma unroll
        for (int kt = 0; kt < 4; ++kt) {
            #pragma unroll
            for (int nt = 0; nt < 4; ++nt) {
                acc[nt] = __builtin_amdgcn_mfma_f32_16x16x32_bf16(ahi[kt], bhi[nt][kt], acc[nt], 0, 0, 0);
                acc[nt] = __builtin_amdgcn_mfma_f32_16x16x32_bf16(alo[kt], bhi[nt][kt], acc[nt], 0, 0, 0);
                acc[nt] = __builtin_amdgcn_mfma_f32_16x16x32_bf16(ahi[kt], blo[nt][kt], acc[nt], 0, 0, 0);
            }
        }

        #pragma unroll
        for (int nt = 0; nt < 4; ++nt) {
            #pragma unroll
            for (int r = 0; r < 4; ++r)
                os[q * 4 + r][wv * 64 + nt * 16 + l15] = acc[nt][r];
        }
        __syncthreads();

        #pragma unroll
        for (int i = tid * 4; i < 16 * 512; i += 2048) {
            const int row = i >> 9, col = i & 511;
            float4 v = *(const float4*)&os[row][col];
            v.x += bias4.x; v.y += bias4.y; v.z += bias4.z; v.w += bias4.w;
            *(float4*)&P[(size_t)(r0 + row) * 512 + col] = v;
        }
        __syncthreads();
    }
}

// ============================================================
// K1: word BiLSTM recurrence via MFMA, split-bf16. Unchanged R11/R12.
// ============================================================
__global__ __launch_bounds__(512, 2) void k_word_lstm(
    const int* __restrict__ ids,
    const float* __restrict__ Whh_f, const float* __restrict__ Whh_b)
{
    const int dir = blockIdx.x & 1;
    const int s0  = (blockIdx.x >> 1) * MT;
    const float* Whh = dir ? Whh_b : Whh_f;
    const float* Pp  = g_P + (size_t)dir * V * 512;

    __shared__ ushort_t sh_hhi[MT][136];
    __shared__ ushort_t sh_hlo[MT][136];
    __shared__ float    sh_g[MT][514];
    __shared__ int      ids_sh[MT * W];

    const int tid  = threadIdx.x;
    const int wv   = tid >> 6;
    const int lane = tid & 63;
    const int l15  = lane & 15;
    const int q    = lane >> 4;
    const int j    = tid & 127;
    const int sgrp = tid >> 7;

    short8 bhi[4][4], blo[4][4];
    #pragma unroll
    for (int nt = 0; nt < 4; ++nt) {
        const float* wrow = Whh + (size_t)(wv * 64 + nt * 16 + l15) * H;
        #pragma unroll
        for (int kt = 0; kt < 4; ++kt) {
            const float* wp = wrow + kt * 32 + q * 8;
            short8 h8, l8;
            #pragma unroll
            for (int i = 0; i < 8; ++i) {
                float f = wp[i];
                ushort_t hb = f2bf(f);
                h8[i] = (short)hb;
                l8[i] = (short)f2bf(f - bf2f(hb));
            }
            bhi[nt][kt] = h8;
            blo[nt][kt] = l8;
        }
    }

    for (int i = tid; i < MT * W; i += 512) ids_sh[i] = ids[s0 * W + i];
    for (int i = tid; i < MT * 136; i += 512) { (&sh_hhi[0][0])[i] = 0; (&sh_hlo[0][0])[i] = 0; }

    float cst[4] = {0.f, 0.f, 0.f, 0.f};
    __syncthreads();

    for (int st = 0; st < W; ++st) {
        const int t = dir ? (W - 1 - st) : st;

        float pg[4][4];
        #pragma unroll
        for (int r = 0; r < 4; ++r) {
            const int s = sgrp * 4 + r;
            const float* Pr = Pp + (size_t)ids_sh[s * W + t] * 512 + j;
            #pragma unroll
            for (int g = 0; g < 4; ++g) pg[r][g] = Pr[g * 128];
        }

        short8 ahi[4], alo[4];
        {
            const ushort_t* ph = &sh_hhi[l15][q * 8];
            const ushort_t* pl = &sh_hlo[l15][q * 8];
            #pragma unroll
            for (int kt = 0; kt < 4; ++kt) {
                ahi[kt] = *(const short8*)(ph + kt * 32);
                alo[kt] = *(const short8*)(pl + kt * 32);
            }
        }

        f32x4 acc[4];
        #pragma unroll
        for (int nt = 0; nt < 4; ++nt) acc[nt] = (f32x4){0.f, 0.f, 0.f, 0.f};
        #pragma unroll
        for (int kt = 0; kt < 4; ++kt) {
            #pragma unroll
            for (int nt = 0; nt < 4; ++nt) {
                acc[nt] = __builtin_amdgcn_mfma_f32_16x16x32_bf16(ahi[kt], bhi[nt][kt], acc[nt], 0, 0, 0);
                acc[nt] = __builtin_amdgcn_mfma_f32_16x16x32_bf16(alo[kt], bhi[nt][kt], acc[nt], 0, 0, 0);
                acc[nt] = __builtin_amdgcn_mfma_f32_16x16x32_bf16(ahi[kt], blo[nt][kt], acc[nt], 0, 0, 0);
            }
        }

        #pragma unroll
        for (int nt = 0; nt < 4; ++nt) {
            #pragma unroll
            for (int r = 0; r < 4; ++r)
                sh_g[q * 4 + r][wv * 64 + nt * 16 + l15] = acc[nt][r];
        }
        __syncthreads();

        #pragma unroll
        for (int r = 0; r < 4; ++r) {
            const int s = sgrp * 4 + r;
            float gi = sh_g[s][j      ] + pg[r][0];
            float gf = sh_g[s][j + 128] + pg[r][1];
            float gg = sh_g[s][j + 256] + pg[r][2];
            float go = sh_g[s][j + 384] + pg[r][3];
            float c = sigf(gf) * cst[r] + sigf(gi) * tanh_fast(gg);
            float h = sigf(go) * tanh_fast(c);
            cst[r] = c;
            g_wl_h[((size_t)(s0 + s) * W + t) * 256 + dir * H + j] = h;
            ushort_t hb = f2bf(h);
            sh_hhi[s][j] = hb;
            sh_hlo[s][j] = f2bf(h - bf2f(hb));
        }
        __syncthreads();
    }
}

// ============================================================
// K2a: word attention scores via MFMA (split-bf16 3-pass):
// sc[row] = b2 + sum_n W2[n]*tanh(h[row]@W1[n] + b1[n]), rows = NW*W.
// 512 thr = 8 waves; wave wv owns cols n in [16wv,16wv+16) with W1
// hi/lo B-frags persistent. Grid-stride over 16-row tiles (6000).
// Tile: stage h rows -> bf16 hi/lo LDS, frags via ds_read_b128,
// 24 MFMA, tanh*W2, 16-lane shfl reduce + cross-wave LDS reduce.
// ============================================================
__global__ __launch_bounds__(512, 2) void k_word_scores(
    const float* __restrict__ W1, const float* __restrict__ b1,
    const float* __restrict__ W2, const float* __restrict__ b2)
{
    constexpr int NTILE = NW * W / 16;   // 6000
    const int tid  = threadIdx.x;
    const int wv   = tid >> 6;
    const int lane = tid & 63;
    const int l15  = lane & 15;
    const int q    = lane >> 4;

    // persistent B-frags: W1 row n = wv*16+l15 (K=256 -> 8 kt)
    short8 bhi[8], blo[8];
    {
        const float* wrow = W1 + (size_t)(wv * 16 + l15) * 256;
        #pragma unroll
        for (int kt = 0; kt < 8; ++kt) {
            const float* wp = wrow + kt * 32 + q * 8;
            short8 h8, l8;
            #pragma unroll
            for (int i = 0; i < 8; ++i) {
                float f = wp[i];
                ushort_t hb = f2bf(f);
                h8[i] = (short)hb;
                l8[i] = (short)f2bf(f - bf2f(hb));
            }
            bhi[kt] = h8;
            blo[kt] = l8;
        }
    }
    const float b1n = b1[wv * 16 + l15];
    const float w2n = W2[wv * 16 + l15];
    const float b2v = b2[0];

    __shared__ ushort_t xhi[16][264];   // K=256, pad 264 halfwords
    __shared__ ushort_t xlo[16][264];
    __shared__ float    part[8][16];

    for (int tile = blockIdx.x; tile < NTILE; tile += WS_NB) {
        const float* src = g_wl_h + (size_t)tile * 16 * 256;
        // stage + convert: 4096 floats, 2 float4 per thread
        #pragma unroll
        for (int i = tid * 4; i < 16 * 256; i += 2048) {
            const int row = i >> 8, col = i & 255;
            float4 v = *(const float4*)&src[i];
            ushort_t h0 = f2bf(v.x), h1 = f2bf(v.y), h2 = f2bf(v.z), h3 = f2bf(v.w);
            *(ushort4*)&xhi[row][col] = make_ushort4(h0, h1, h2, h3);
            *(ushort4*)&xlo[row][col] = make_ushort4(
                f2bf(v.x - bf2f(h0)), f2bf(v.y - bf2f(h1)),
                f2bf(v.z - bf2f(h2)), f2bf(v.w - bf2f(h3)));
        }
        __syncthreads();

        short8 ahi[8], alo[8];
        {
            const ushort_t* ph = &xhi[l15][q * 8];
            const ushort_t* pl = &xlo[l15][q * 8];
            #pragma unroll
            for (int kt = 0; kt < 8; ++kt) {
                ahi[kt] = *(const short8*)(ph + kt * 32);
                alo[kt] = *(const short8*)(pl + kt * 32);
            }
        }

        f32x4 acc = (f32x4){0.f, 0.f, 0.f, 0.f};
        #pragma unroll
        for (int kt = 0; kt < 8; ++kt) {
            acc = __builtin_amdgcn_mfma_f32_16x16x32_bf16(ahi[kt], bhi[kt], acc, 0, 0, 0);
            acc = __builtin_amdgcn_mfma_f32_16x16x32_bf16(alo[kt], bhi[kt], acc, 0, 0, 0);
            acc = __builtin_amdgcn_mfma_f32_16x16x32_bf16(ahi[kt], blo[kt], acc, 0, 0, 0);
        }

        // u = tanh(acc + b1[n]) * W2[n]; reduce over the wave's 16 cols
        float vr[4];
        #pragma unroll
        for (int r = 0; r < 4; ++r) {
            float v = tanh_fast(acc[r] + b1n) * w2n;
            v += __shfl_xor(v, 1, 64);
            v += __shfl_xor(v, 2, 64);
            v += __shfl_xor(v, 4, 64);
            v += __shfl_xor(v, 8, 64);
            vr[r] = v;
        }
        if (l15 == 0) {
            #pragma unroll
            for (int r = 0; r < 4; ++r) part[wv][q * 4 + r] = vr[r];
        }
        __syncthreads();

        if (tid < 16) {
            float s = b2v;
            #pragma unroll
            for (int w = 0; w < 8; ++w) s += part[w][tid];
            g_wsc[tile * 16 + tid] = s;
        }
        __syncthreads();
    }
}

// ============================================================
// K2b: word pool: mask + softmax of precomputed scores + weighted sum
// streaming h from global. grid NW, 128 thr.
// ============================================================
__global__ __launch_bounds__(128) void k_word_pool(const int* __restrict__ ids)
{
    const int n = blockIdx.x;
    __shared__ float wsh[W];
    const int tid = threadIdx.x;

    if (tid < W) {
        bool valid = (ids[n * W + tid] != 0);
        wsh[tid] = valid ? g_wsc[(size_t)n * W + tid] : -INFINITY;
    }
    __syncthreads();
    if (tid == 0) {
        float m = -INFINITY;
        for (int t = 0; t < W; ++t) m = fmaxf(m, wsh[t]);
        float sum = 0.f;
        for (int t = 0; t < W; ++t) sum += (wsh[t] == -INFINITY) ? 0.f : __expf(wsh[t] - m);
        const float inv = (sum > 0.f) ? 1.f / sum : 0.f;
        for (int t = 0; t < W; ++t) wsh[t] = (wsh[t] == -INFINITY) ? 0.f : __expf(wsh[t] - m) * inv;
    }
    __syncthreads();

    const float* src = g_wl_h + (size_t)n * W * 256;
    float o0 = 0.f, o1 = 0.f;
    #pragma unroll
    for (int t = 0; t < W; ++t) {
        float w = wsh[t];
        o0 += w * src[t * 256 + tid];
        o1 += w * src[t * 256 + tid + 128];
    }
    g_sent[(size_t)n * 256 + tid] = o0;
    g_sent[(size_t)n * 256 + tid + 128] = o1;
}

// ============================================================
// K3: sentence LSTM input projection. grid 800, 256 thr. Unchanged.
// ============================================================
__global__ __launch_bounds__(256) void k_sl_gin(
    const float* __restrict__ Wih_f, const float* __restrict__ bih_f, const float* __restrict__ bhh_f,
    const float* __restrict__ Wih_b, const float* __restrict__ bih_b, const float* __restrict__ bhh_b)
{
    const int dir = blockIdx.x & 1;
    const float* Wih = dir ? Wih_b : Wih_f;
    const float* bih = dir ? bih_b : bih_f;
    const float* bhh = dir ? bhh_b : bhh_f;
    float* gin = dir ? g_gin_b : g_gin_f;
    const int r0 = (blockIdx.x >> 1) * NSEQ_G;

    __shared__ float xs[NSEQ_G][256];
    const int tid = threadIdx.x;
    for (int i = tid * 4; i < NSEQ_G * 256; i += 1024)
        *(float4*)&(&xs[0][0])[i] = *(const float4*)&g_sent[(size_t)r0 * 256 + i];
    __syncthreads();

    const int g0 = tid, g1 = tid + 256;
    float acc0[NSEQ_G], acc1[NSEQ_G];
    #pragma unroll
    for (int s = 0; s < NSEQ_G; ++s) { acc0[s] = 0.f; acc1[s] = 0.f; }
    const float* w0 = &Wih[g0 * 256]; const float* w1 = &Wih[g1 * 256];
    for (int k = 0; k < 256; k += 4) {
        float4 wa = *(const float4*)(w0 + k);
        float4 wb = *(const float4*)(w1 + k);
        #pragma unroll
        for (int s = 0; s < NSEQ_G; ++s) {
            float4 xv = *(const float4*)&xs[s][k];
            acc0[s] += dot4(wa, xv);
            acc1[s] += dot4(wb, xv);
        }
    }
    const float bv0 = bih[g0] + bhh[g0];
    const float bv1 = bih[g1] + bhh[g1];
    #pragma unroll
    for (int s = 0; s < NSEQ_G; ++s) {
        gin[(size_t)(r0 + s) * 512 + g0] = acc0[s] + bv0;
        gin[(size_t)(r0 + s) * 512 + g1] = acc1[s] + bv1;
    }
}

// ============================================================
// K4: sentence BiLSTM, owns-cell, 1 seq/block. grid 128, 128 thr. Unchanged.
// ============================================================
__global__ __launch_bounds__(128) void k_sent_lstm(
    const float* __restrict__ Whh_f, const float* __restrict__ Whh_b)
{
    const int dir = blockIdx.x & 1;
    const int b   = blockIdx.x >> 1;
    const float* Whh = dir ? Whh_b : Whh_f;
    const float* gin = dir ? g_gin_b : g_gin_f;

    __shared__ float hs[2][H];
    const int j = threadIdx.x;
    const float* wr0 = Whh + (size_t)(j      ) * H;
    const float* wr1 = Whh + (size_t)(j + 128) * H;
    const float* wr2 = Whh + (size_t)(j + 256) * H;
    const float* wr3 = Whh + (size_t)(j + 384) * H;

    hs[0][j] = 0.f;
    float cst = 0.f;
    __syncthreads();

    int cur = 0;
    for (int st = 0; st < S; ++st) {
        const int t = dir ? (S - 1 - st) : st;
        const float* gp = gin + (size_t)(b * S + t) * 512;
        float p0 = gp[j], p1 = gp[j + 128], p2 = gp[j + 256], p3 = gp[j + 384];

        float a0 = 0.f, a1 = 0.f, a2 = 0.f, a3 = 0.f;
        for (int k = 0; k < H; k += 4) {
            float4 hv = *(const float4*)&hs[cur][k];
            a0 += dot4(*(const float4*)(wr0 + k), hv);
            a1 += dot4(*(const float4*)(wr1 + k), hv);
            a2 += dot4(*(const float4*)(wr2 + k), hv);
            a3 += dot4(*(const float4*)(wr3 + k), hv);
        }
        float c = sigf(a1 + p1) * cst + sigf(a0 + p0) * tanh_fast(a2 + p2);
        float h = sigf(a3 + p3) * tanh_fast(c);
        cst = c;
        hs[cur ^ 1][j] = h;
        g_sl_h[(size_t)(b * S + t) * 256 + dir * H + j] = h;
        __syncthreads();
        cur ^= 1;
    }
}

// ============================================================
// K5: document attention pool, SINGLE-PASS (51.2 KB LDS). Unchanged.
// ============================================================
template <int T>
__global__ __launch_bounds__(128) void k_attn_pool_doc(
    const int* __restrict__ ids,
    const float* __restrict__ W1, const float* __restrict__ b1,
    const float* __restrict__ W2, const float* __restrict__ b2)
{
    constexpr int TH = T / 2;
    const int n = blockIdx.x;
    __shared__ float hsh[T][256];
    __shared__ float wsh[T];
    const int tid = threadIdx.x;
    const int lane = tid & 63;
    const int wv   = tid >> 6;

    const float* src = g_sl_h + (size_t)n * T * 256;
    for (int i = tid * 4; i < T * 256; i += 512)
        *(float4*)&(&hsh[0][0])[i] = *(const float4*)&src[i];
    __syncthreads();

    const int j0 = lane, j1 = lane + 64;
    const int tbase = wv * TH;
    float acc0[TH], acc1[TH];
    #pragma unroll
    for (int u = 0; u < TH; ++u) { acc0[u] = 0.f; acc1[u] = 0.f; }
    const float* w1a = &W1[j0 * 256];
    const float* w1b = &W1[j1 * 256];
    for (int k = 0; k < 256; k += 4) {
        float4 wa = *(const float4*)(w1a + k);
        float4 wb = *(const float4*)(w1b + k);
        #pragma unroll
        for (int u = 0; u < TH; ++u) {
            float4 hv = *(const float4*)&hsh[tbase + u][k];
            acc0[u] += dot4(wa, hv);
            acc1[u] += dot4(wb, hv);
        }
    }
    const float b1a = b1[j0], b1b = b1[j1];
    const float w2a = W2[j0], w2b = W2[j1];
    #pragma unroll
    for (int u = 0; u < TH; ++u) {
        float v = w2a * tanh_fast(acc0[u] + b1a) + w2b * tanh_fast(acc1[u] + b1b);
        #pragma unroll
        for (int off = 32; off > 0; off >>= 1) v += __shfl_down(v, off, 64);
        if (lane == 0) wsh[tbase + u] = v;
    }
    __syncthreads();

    if (tid < T) {
        bool valid = false;
        const int* ip = &ids[((size_t)n * T + tid) * W];
        for (int w = 0; w < W; ++w) valid |= (ip[w] != 0);
        wsh[tid] = valid ? (wsh[tid] + b2[0]) : -INFINITY;
    }
    __syncthreads();
    if (tid == 0) {
        float m = -INFINITY;
        for (int t = 0; t < T; ++t) m = fmaxf(m, wsh[t]);
        float sum = 0.f;
        for (int t = 0; t < T; ++t) sum += (wsh[t] == -INFINITY) ? 0.f : __expf(wsh[t] - m);
        const float inv = (sum > 0.f) ? 1.f / sum : 0.f;
        for (int t = 0; t < T; ++t) wsh[t] = (wsh[t] == -INFINITY) ? 0.f : __expf(wsh[t] - m) * inv;
    }
    __syncthreads();

    float o0 = 0.f, o1 = 0.f;
    #pragma unroll
    for (int t = 0; t < T; ++t) {
        float w = wsh[t];
        o0 += w * hsh[t][tid];
        o1 += w * hsh[t][tid + 128];
    }
    g_doc[(size_t)n * 256 + tid] = o0;
    g_doc[(size_t)n * 256 + tid + 128] = o1;
}

// ============================================================
// K6: classifier (fp32 out). grid B, 128 thr. Unchanged.
// ============================================================
__global__ __launch_bounds__(128) void k_classifier(
    const float* __restrict__ W1, const float* __restrict__ b1,
    const float* __restrict__ W2, const float* __restrict__ b2,
    float* __restrict__ out)
{
    const int b = blockIdx.x;
    __shared__ float dsh[256];
    __shared__ float hsh[128];
    const int tid = threadIdx.x;
    if (tid < 64) *(float4*)&dsh[tid * 4] = *(const float4*)&g_doc[(size_t)b * 256 + tid * 4];
    __syncthreads();
    float acc = 0.f;
    const float* w1p = &W1[tid * 256];
    for (int k = 0; k < 256; k += 4) {
        float4 w4 = *(const float4*)(w1p + k);
        float4 d4 = *(const float4*)&dsh[k];
        acc += dot4(w4, d4);
    }
    hsh[tid] = fmaxf(acc + b1[tid], 0.f);
    __syncthreads();
    if (tid < 3) {
        float a = b2[tid];
        const float* w2p = &W2[tid * 128];
        for (int j = 0; j < 128; ++j) a += w2p[j] * hsh[j];
        out[b * 3 + tid] = a;
    }
}

// ============================================================
extern "C" void kernel_launch(void* const* d_in, const int* in_sizes, int n_in,
                              void* d_out, int out_size, void* d_ws, size_t ws_size,
                              hipStream_t stream) {
    const int*   ids      = (const int*)d_in[0];
    const float* emb      = (const float*)d_in[1];
    const float* wl_Wih_f = (const float*)d_in[2];
    const float* wl_Whh_f = (const float*)d_in[3];
    const float* wl_bih_f = (const float*)d_in[4];
    const float* wl_bhh_f = (const float*)d_in[5];
    const float* wl_Wih_b = (const float*)d_in[6];
    const float* wl_Whh_b = (const float*)d_in[7];
    const float* wl_bih_b = (const float*)d_in[8];
    const float* wl_bhh_b = (const float*)d_in[9];
    const float* sl_Wih_f = (const float*)d_in[10];
    const float* sl_Whh_f = (const float*)d_in[11];
    const float* sl_bih_f = (const float*)d_in[12];
    const float* sl_bhh_f = (const float*)d_in[13];
    const float* sl_Wih_b = (const float*)d_in[14];
    const float* sl_Whh_b = (const float*)d_in[15];
    const float* sl_bih_b = (const float*)d_in[16];
    const float* sl_bhh_b = (const float*)d_in[17];
    const float* wa_W1 = (const float*)d_in[18];
    const float* wa_b1 = (const float*)d_in[19];
    const float* wa_W2 = (const float*)d_in[20];
    const float* wa_b2 = (const float*)d_in[21];
    const float* sa_W1 = (const float*)d_in[22];
    const float* sa_b1 = (const float*)d_in[23];
    const float* sa_W2 = (const float*)d_in[24];
    const float* sa_b2 = (const float*)d_in[25];
    const float* cl_W1 = (const float*)d_in[26];
    const float* cl_b1 = (const float*)d_in[27];
    const float* cl_W2 = (const float*)d_in[28];
    const float* cl_b2 = (const float*)d_in[29];

    k_emb_proj<<<EP_NB * 2, 512, 0, stream>>>(
        emb, wl_Wih_f, wl_bih_f, wl_bhh_f, wl_Wih_b, wl_bih_b, wl_bhh_b);

    k_word_lstm<<<NW / MT * 2, 512, 0, stream>>>(ids, wl_Whh_f, wl_Whh_b);

    k_word_scores<<<WS_NB, 512, 0, stream>>>(wa_W1, wa_b1, wa_W2, wa_b2);

    k_word_pool<<<NW, 128, 0, stream>>>(ids);

    k_sl_gin<<<NW / NSEQ_G * 2, 256, 0, stream>>>(
        sl_Wih_f, sl_bih_f, sl_bhh_f, sl_Wih_b, sl_bih_b, sl_bhh_b);

    k_sent_lstm<<<B * 2, 128, 0, stream>>>(sl_Whh_f, sl_Whh_b);

    k_attn_pool_doc<S><<<B, 128, 0, stream>>>(ids, sa_W1, sa_b1, sa_W2, sa_b2);

    k_classifier<<<B, 128, 0, stream>>>(cl_W1, cl_b1, cl_W2, cl_b2, (float*)d_out);
}